// Round 1
// baseline (4380.574 us; speedup 1.0000x reference)
//
#include <hip/hip_runtime.h>
#include <math.h>

namespace {
constexpr int kV = 128000, kD = 512, kNH = 8, kNL = 2, kHID = 1408;
constexpr int kHD = 64, kHALF = 32, kB = 4, kT = 508, kNLAB = 5, kLBL = 4;
constexpr int kS = 512;                 // T + LBL
constexpr int kNSeq = kNLAB * kB;       // 20
constexpr int kNS = kNSeq * kS;         // 10240 rows
constexpr float kEps = 1e-5f;
constexpr int kVC = 256;                // vocab columns per block (logits partial)
constexpr int kNChunk = kV / kVC;       // 500
constexpr int kRG = 20;                 // rows per register-group in logits partial
}

// ---------------- embedding: build ctx tokens, gather emb rows ----------------
__global__ void k_embed(const int* __restrict__ input_ids, const int* __restrict__ label_ids,
                        const float* __restrict__ emb, float* __restrict__ h) {
  int row = blockIdx.x;                    // 0..kNS-1
  int n = row / kS, s = row - n * kS;      // n = lab*B + b
  int lab = n / kB, b = n - lab * kB;
  int tok = (s < kT) ? input_ids[b * kT + s] : label_ids[lab * kLBL + (s - kT)];
  const float4* src = (const float4*)(emb + (size_t)tok * kD);
  float4* dst = (float4*)(h + (size_t)row * kD);
  for (int i = threadIdx.x; i < kD / 4; i += blockDim.x) dst[i] = src[i];
}

// ---------------- rmsnorm: y = x * rsqrt(mean(x^2)+eps) * w ----------------
__global__ __launch_bounds__(256) void k_rmsnorm(const float* __restrict__ x,
                                                 const float* __restrict__ w,
                                                 float* __restrict__ y) {
  int row = blockIdx.x;
  const float* xr = x + (size_t)row * kD;
  float ss = 0.f;
  for (int i = threadIdx.x; i < kD; i += 256) { float v = xr[i]; ss += v * v; }
  #pragma unroll
  for (int o = 1; o < 64; o <<= 1) ss += __shfl_xor(ss, o);
  __shared__ float wsum[4];
  int lane = threadIdx.x & 63, wid = threadIdx.x >> 6;
  if (lane == 0) wsum[wid] = ss;
  __syncthreads();
  float tot = wsum[0] + wsum[1] + wsum[2] + wsum[3];
  float inv = rsqrtf(tot / (float)kD + kEps);
  for (int i = threadIdx.x; i < kD; i += 256)
    y[(size_t)row * kD + i] = xr[i] * inv * w[i];
}

// ---------------- generic fp32 GEMM: C[M,N] (+)= A[M,K] @ B[K,N] ----------------
// 64x64 block tile, 256 threads, 4x4 per thread, K-tile 16. M,N,K multiples of 64/16.
template<int MODE>  // 0: C = A@B   1: C += A@B
__global__ __launch_bounds__(256) void k_gemm(const float* __restrict__ A,
                                              const float* __restrict__ Bm,
                                              float* __restrict__ C,
                                              int M, int N, int K) {
  __shared__ float As[16][64];
  __shared__ float Bs[16][64];
  int row0 = blockIdx.y * 64, col0 = blockIdx.x * 64;
  int tx = threadIdx.x & 15, ty = threadIdx.x >> 4;
  float acc[4][4] = {};
  for (int k0 = 0; k0 < K; k0 += 16) {
    #pragma unroll
    for (int i = 0; i < 4; i++) {
      int idx = threadIdx.x + i * 256;
      int am = idx >> 4, ak = idx & 15;
      As[ak][am] = A[(size_t)(row0 + am) * K + (k0 + ak)];
      int bk = idx >> 6, bn = idx & 63;
      Bs[bk][bn] = Bm[(size_t)(k0 + bk) * N + (col0 + bn)];
    }
    __syncthreads();
    #pragma unroll
    for (int kk = 0; kk < 16; kk++) {
      float4 a4 = *(const float4*)&As[kk][ty * 4];
      float4 b4 = *(const float4*)&Bs[kk][tx * 4];
      float a[4] = {a4.x, a4.y, a4.z, a4.w};
      float b[4] = {b4.x, b4.y, b4.z, b4.w};
      #pragma unroll
      for (int i = 0; i < 4; i++)
        #pragma unroll
        for (int j = 0; j < 4; j++) acc[i][j] += a[i] * b[j];
    }
    __syncthreads();
  }
  #pragma unroll
  for (int i = 0; i < 4; i++)
    #pragma unroll
    for (int j = 0; j < 4; j++) {
      size_t off = (size_t)(row0 + ty * 4 + i) * N + (col0 + tx * 4 + j);
      if (MODE == 1) C[off] += acc[i][j]; else C[off] = acc[i][j];
    }
}

// ---------------- FFN dual GEMM: act = silu(A@W1) * (A@W3) ----------------
__global__ __launch_bounds__(256) void k_ffn13(const float* __restrict__ A,
                                               const float* __restrict__ W1,
                                               const float* __restrict__ W3,
                                               float* __restrict__ act,
                                               int M, int N, int K) {
  __shared__ float As[16][64];
  __shared__ float B1s[16][64];
  __shared__ float B3s[16][64];
  int row0 = blockIdx.y * 64, col0 = blockIdx.x * 64;
  int tx = threadIdx.x & 15, ty = threadIdx.x >> 4;
  float acc1[4][4] = {}, acc2[4][4] = {};
  for (int k0 = 0; k0 < K; k0 += 16) {
    #pragma unroll
    for (int i = 0; i < 4; i++) {
      int idx = threadIdx.x + i * 256;
      int am = idx >> 4, ak = idx & 15;
      As[ak][am] = A[(size_t)(row0 + am) * K + (k0 + ak)];
      int bk = idx >> 6, bn = idx & 63;
      B1s[bk][bn] = W1[(size_t)(k0 + bk) * N + (col0 + bn)];
      B3s[bk][bn] = W3[(size_t)(k0 + bk) * N + (col0 + bn)];
    }
    __syncthreads();
    #pragma unroll
    for (int kk = 0; kk < 16; kk++) {
      float4 a4 = *(const float4*)&As[kk][ty * 4];
      float4 b4 = *(const float4*)&B1s[kk][tx * 4];
      float4 c4 = *(const float4*)&B3s[kk][tx * 4];
      float a[4] = {a4.x, a4.y, a4.z, a4.w};
      float b[4] = {b4.x, b4.y, b4.z, b4.w};
      float c[4] = {c4.x, c4.y, c4.z, c4.w};
      #pragma unroll
      for (int i = 0; i < 4; i++)
        #pragma unroll
        for (int j = 0; j < 4; j++) {
          acc1[i][j] += a[i] * b[j];
          acc2[i][j] += a[i] * c[j];
        }
    }
    __syncthreads();
  }
  #pragma unroll
  for (int i = 0; i < 4; i++)
    #pragma unroll
    for (int j = 0; j < 4; j++) {
      size_t off = (size_t)(row0 + ty * 4 + i) * N + (col0 + tx * 4 + j);
      float aa = acc1[i][j];
      float sg = 1.f / (1.f + expf(-aa));
      act[off] = aa * sg * acc2[i][j];
    }
}

// ---------------- RoPE (in-place on q and k) ----------------
__global__ void k_rope(float* __restrict__ q, float* __restrict__ k) {
  int idx = blockIdx.x * blockDim.x + threadIdx.x;  // kNS*kNH*kHALF threads
  if (idx >= kNS * kNH * kHALF) return;
  int d = idx & (kHALF - 1);
  int t = idx >> 5;
  int hh = t & (kNH - 1);
  int row = t >> 3;
  int s = row & (kS - 1);
  float freq = expf(-logf(10000.f) * ((float)d / (float)kHALF));
  float ang = (float)s * freq;
  float c = cosf(ang), sn = sinf(ang);
  size_t base = (size_t)row * kD + hh * kHD + d;
  float x1 = q[base], x2 = q[base + kHALF];
  q[base]         = x1 * c - x2 * sn;
  q[base + kHALF] = x1 * sn + x2 * c;
  x1 = k[base]; x2 = k[base + kHALF];
  k[base]         = x1 * c - x2 * sn;
  k[base + kHALF] = x1 * sn + x2 * c;
}

// ---------------- causal attention, one wave per (n, h, query-row) ----------------
__global__ __launch_bounds__(64) void k_attn(const float* __restrict__ q,
                                             const float* __restrict__ k,
                                             const float* __restrict__ v,
                                             float* __restrict__ o) {
  int bid = blockIdx.x;
  int s = bid & (kS - 1);
  int nh = bid >> 9;
  int hh = nh & (kNH - 1);
  int n = nh >> 3;
  int lane = threadIdx.x;
  __shared__ float sc[kS];
  __shared__ float qs[kHD];
  size_t qoff = ((size_t)(n * kS + s) * kNH + hh) * kHD;
  qs[lane] = q[qoff + lane] * 0.125f;   // 1/sqrt(64)
  __syncthreads();
  for (int j = lane; j <= s; j += 64) {
    const float* kr = k + ((size_t)(n * kS + j) * kNH + hh) * kHD;
    float dot = 0.f;
    #pragma unroll
    for (int d2 = 0; d2 < kHD; d2++) dot += qs[d2] * kr[d2];
    sc[j] = dot;
  }
  __syncthreads();
  float m = -1e30f;
  for (int j = lane; j <= s; j += 64) m = fmaxf(m, sc[j]);
  #pragma unroll
  for (int o2 = 1; o2 < 64; o2 <<= 1) m = fmaxf(m, __shfl_xor(m, o2));
  float sum = 0.f;
  for (int j = lane; j <= s; j += 64) { float p = expf(sc[j] - m); sc[j] = p; sum += p; }
  #pragma unroll
  for (int o2 = 1; o2 < 64; o2 <<= 1) sum += __shfl_xor(sum, o2);
  float inv = 1.f / sum;
  __syncthreads();
  float accv = 0.f;
  for (int j = 0; j <= s; j++) {
    const float* vr = v + ((size_t)(n * kS + j) * kNH + hh) * kHD;
    accv += sc[j] * vr[lane];
  }
  o[qoff + lane] = accv * inv;
}

// ---------------- gather the 80 scoring rows (post final-norm) ----------------
__global__ void k_gather(const float* __restrict__ xn, float* __restrict__ hs) {
  int r = blockIdx.x;                       // 0..79 : r = n*LBL + li
  int n = r / kLBL, li = r - n * kLBL;
  size_t src = ((size_t)n * kS + (kT - 1 + li)) * kD;
  for (int i = threadIdx.x; i < kD; i += blockDim.x) hs[r * kD + i] = xn[src + i];
}

// ---------------- logits partials: per vocab-chunk (max, sumexp) for all 80 rows ----------------
__global__ __launch_bounds__(256) void k_logits_partial(const float* __restrict__ hs,
                                                        const float* __restrict__ lm,
                                                        float* __restrict__ part) {
  __shared__ float hss[kRG * kD];           // 40 KB, reused as reduce scratch
  int v = blockIdx.x * kVC + threadIdx.x;
  int tid = threadIdx.x, lane = tid & 63, wid = tid >> 6;
  for (int g = 0; g < 4; g++) {
    for (int i = tid; i < kRG * kD; i += 256) hss[i] = hs[g * kRG * kD + i];
    __syncthreads();
    float acc[kRG];
    #pragma unroll
    for (int r = 0; r < kRG; r++) acc[r] = 0.f;
    for (int d2 = 0; d2 < kD; d2++) {
      float wv = lm[(size_t)d2 * kV + v];
      #pragma unroll
      for (int r = 0; r < kRG; r++) acc[r] += hss[r * kD + d2] * wv;
    }
    __syncthreads();
    #pragma unroll
    for (int r = 0; r < kRG; r++) hss[r * 256 + tid] = acc[r];
    __syncthreads();
    for (int r = wid; r < kRG; r += 4) {
      float a0 = hss[r * 256 + lane],       a1 = hss[r * 256 + lane + 64];
      float a2 = hss[r * 256 + lane + 128], a3 = hss[r * 256 + lane + 192];
      float mx = fmaxf(fmaxf(a0, a1), fmaxf(a2, a3));
      #pragma unroll
      for (int o2 = 1; o2 < 64; o2 <<= 1) mx = fmaxf(mx, __shfl_xor(mx, o2));
      float se = expf(a0 - mx) + expf(a1 - mx) + expf(a2 - mx) + expf(a3 - mx);
      #pragma unroll
      for (int o2 = 1; o2 < 64; o2 <<= 1) se += __shfl_xor(se, o2);
      if (lane == 0) {
        size_t pi = ((size_t)(g * kRG + r) * kNChunk + blockIdx.x) * 2;
        part[pi] = mx; part[pi + 1] = se;
      }
    }
    __syncthreads();
  }
}

// ---------------- label-token logits ----------------
__global__ __launch_bounds__(64) void k_label_logits(const float* __restrict__ hs,
                                                     const float* __restrict__ lm,
                                                     const int* __restrict__ label_ids,
                                                     float* __restrict__ lbl) {
  int r = blockIdx.x;                       // 0..79
  int li = r & 3, n = r >> 2, lab = n / kB;
  int tok = label_ids[lab * kLBL + li];
  int lane = threadIdx.x;
  float dv = 0.f;
  for (int d2 = lane; d2 < kD; d2 += 64) dv += hs[r * kD + d2] * lm[(size_t)d2 * kV + tok];
  #pragma unroll
  for (int o2 = 1; o2 < 64; o2 <<= 1) dv += __shfl_xor(dv, o2);
  if (lane == 0) lbl[r] = dv;
}

// ---------------- final reduce: logsumexp combine + output ----------------
__global__ __launch_bounds__(64) void k_final(const float* __restrict__ part,
                                              const float* __restrict__ lbl,
                                              float* __restrict__ out) {
  int n = blockIdx.x;                       // 0..19, n = lab*B + b
  int lab = n / kB, b = n - lab * kB;
  int lane = threadIdx.x;
  float res = 0.f;
  for (int li = 0; li < kLBL; li++) {
    int r = n * kLBL + li;
    const float* pr = part + (size_t)r * kNChunk * 2;
    float mx = -1e30f;
    for (int c = lane; c < kNChunk; c += 64) mx = fmaxf(mx, pr[c * 2]);
    #pragma unroll
    for (int o2 = 1; o2 < 64; o2 <<= 1) mx = fmaxf(mx, __shfl_xor(mx, o2));
    float sum = 0.f;
    for (int c = lane; c < kNChunk; c += 64) sum += pr[c * 2 + 1] * expf(pr[c * 2] - mx);
    #pragma unroll
    for (int o2 = 1; o2 < 64; o2 <<= 1) sum += __shfl_xor(sum, o2);
    res += lbl[r] - (mx + logf(sum));
  }
  if (lane == 0) out[b * kNLAB + lab] = res;
}

extern "C" void kernel_launch(void* const* d_in, const int* in_sizes, int n_in,
                              void* d_out, int out_size, void* d_ws, size_t ws_size,
                              hipStream_t stream) {
  const int*   input_ids    = (const int*)d_in[0];
  const int*   label_ids    = (const int*)d_in[1];
  const float* emb          = (const float*)d_in[2];
  const float* wq           = (const float*)d_in[3];
  const float* wk           = (const float*)d_in[4];
  const float* wv           = (const float*)d_in[5];
  const float* wo           = (const float*)d_in[6];
  const float* w1           = (const float*)d_in[7];
  const float* w2           = (const float*)d_in[8];
  const float* w3           = (const float*)d_in[9];
  const float* attn_norm_w  = (const float*)d_in[10];
  const float* ffn_norm_w   = (const float*)d_in[11];
  const float* final_norm_w = (const float*)d_in[12];
  const float* lm_head      = (const float*)d_in[13];
  float* out = (float*)d_out;

  char* ws = (char*)d_ws;
  float* h    = (float*)(ws);                 // 20,971,520 B
  float* xn   = (float*)(ws + 20971520);      // 20,971,520
  float* q    = (float*)(ws + 41943040);      // 20,971,520
  float* kk   = (float*)(ws + 62914560);      // 20,971,520
  float* vv   = (float*)(ws + 83886080);      // 20,971,520
  float* big  = (float*)(ws + 104857600);     // 57,671,680 (attn-out / ffn act)
  float* hs   = (float*)(ws + 162529280);     // 163,840
  float* part = (float*)(ws + 162693120);     // 320,000
  float* lbl  = (float*)(ws + 163013120);     // 320

  k_embed<<<kNS, 128, 0, stream>>>(input_ids, label_ids, emb, h);

  for (int l = 0; l < kNL; l++) {
    k_rmsnorm<<<kNS, 256, 0, stream>>>(h, attn_norm_w + (size_t)l * kD, xn);
    dim3 gqkv(kD / 64, kNS / 64);
    k_gemm<0><<<gqkv, 256, 0, stream>>>(xn, wq + (size_t)l * kD * kD, q,  kNS, kD, kD);
    k_gemm<0><<<gqkv, 256, 0, stream>>>(xn, wk + (size_t)l * kD * kD, kk, kNS, kD, kD);
    k_gemm<0><<<gqkv, 256, 0, stream>>>(xn, wv + (size_t)l * kD * kD, vv, kNS, kD, kD);
    k_rope<<<(kNS * kNH * kHALF) / 256, 256, 0, stream>>>(q, kk);
    k_attn<<<kNSeq * kNH * kS, 64, 0, stream>>>(q, kk, vv, big);
    k_gemm<1><<<gqkv, 256, 0, stream>>>(big, wo + (size_t)l * kD * kD, h, kNS, kD, kD);
    k_rmsnorm<<<kNS, 256, 0, stream>>>(h, ffn_norm_w + (size_t)l * kD, xn);
    dim3 gffn(kHID / 64, kNS / 64);
    k_ffn13<<<gffn, 256, 0, stream>>>(xn, w1 + (size_t)l * kD * kHID,
                                      w3 + (size_t)l * kD * kHID, big, kNS, kHID, kD);
    dim3 gw2(kD / 64, kNS / 64);
    k_gemm<1><<<gw2, 256, 0, stream>>>(big, w2 + (size_t)l * kHID * kD, h, kNS, kD, kHID);
  }

  k_rmsnorm<<<kNS, 256, 0, stream>>>(h, final_norm_w, xn);
  k_gather<<<kNSeq * kLBL, 128, 0, stream>>>(xn, hs);
  k_logits_partial<<<kNChunk, 256, 0, stream>>>(hs, lm_head, part);
  k_label_logits<<<kNSeq * kLBL, 64, 0, stream>>>(hs, lm_head, label_ids, lbl);
  k_final<<<kNSeq, 64, 0, stream>>>(part, lbl, out);
}

// Round 2
// 3027.933 us; speedup vs baseline: 1.4467x; 1.4467x over previous
//
#include <hip/hip_runtime.h>
#include <math.h>

namespace {
constexpr int kV = 128000, kD = 512, kNH = 8, kNL = 2, kHID = 1408;
constexpr int kHD = 64, kHALF = 32, kB = 4, kT = 508, kNLAB = 5, kLBL = 4;
constexpr int kS = 512;                 // T + LBL
constexpr int kNSeq = kNLAB * kB;       // 20
constexpr int kNS = kNSeq * kS;         // 10240 rows
constexpr float kEps = 1e-5f;
constexpr int kVC = 256;                // vocab columns per block (logits partial)
constexpr int kNChunk = kV / kVC;       // 500
constexpr int kRG = 20;                 // rows per register-group in logits partial
}

// ---------------- embedding: build ctx tokens, gather emb rows ----------------
__global__ void k_embed(const int* __restrict__ input_ids, const int* __restrict__ label_ids,
                        const float* __restrict__ emb, float* __restrict__ h) {
  int row = blockIdx.x;                    // 0..kNS-1
  int n = row / kS, s = row - n * kS;      // n = lab*B + b
  int lab = n / kB, b = n - lab * kB;
  int tok = (s < kT) ? input_ids[b * kT + s] : label_ids[lab * kLBL + (s - kT)];
  const float4* src = (const float4*)(emb + (size_t)tok * kD);
  float4* dst = (float4*)(h + (size_t)row * kD);
  for (int i = threadIdx.x; i < kD / 4; i += blockDim.x) dst[i] = src[i];
}

// ---------------- rmsnorm: y = x * rsqrt(mean(x^2)+eps) * w ----------------
__global__ __launch_bounds__(256) void k_rmsnorm(const float* __restrict__ x,
                                                 const float* __restrict__ w,
                                                 float* __restrict__ y) {
  int row = blockIdx.x;
  const float* xr = x + (size_t)row * kD;
  float ss = 0.f;
  for (int i = threadIdx.x; i < kD; i += 256) { float v = xr[i]; ss += v * v; }
  #pragma unroll
  for (int o = 1; o < 64; o <<= 1) ss += __shfl_xor(ss, o);
  __shared__ float wsum[4];
  int lane = threadIdx.x & 63, wid = threadIdx.x >> 6;
  if (lane == 0) wsum[wid] = ss;
  __syncthreads();
  float tot = wsum[0] + wsum[1] + wsum[2] + wsum[3];
  float inv = rsqrtf(tot / (float)kD + kEps);
  for (int i = threadIdx.x; i < kD; i += 256)
    y[(size_t)row * kD + i] = xr[i] * inv * w[i];
}

// ---------------- generic fp32 GEMM: C[M,N] (+)= A[M,K] @ B[K,N] ----------------
template<int MODE>  // 0: C = A@B   1: C += A@B
__global__ __launch_bounds__(256) void k_gemm(const float* __restrict__ A,
                                              const float* __restrict__ Bm,
                                              float* __restrict__ C,
                                              int M, int N, int K) {
  __shared__ float As[16][64];
  __shared__ float Bs[16][64];
  int row0 = blockIdx.y * 64, col0 = blockIdx.x * 64;
  int tx = threadIdx.x & 15, ty = threadIdx.x >> 4;
  float acc[4][4] = {};
  for (int k0 = 0; k0 < K; k0 += 16) {
    #pragma unroll
    for (int i = 0; i < 4; i++) {
      int idx = threadIdx.x + i * 256;
      int am = idx >> 4, ak = idx & 15;
      As[ak][am] = A[(size_t)(row0 + am) * K + (k0 + ak)];
      int bk = idx >> 6, bn = idx & 63;
      Bs[bk][bn] = Bm[(size_t)(k0 + bk) * N + (col0 + bn)];
    }
    __syncthreads();
    #pragma unroll
    for (int kk = 0; kk < 16; kk++) {
      float4 a4 = *(const float4*)&As[kk][ty * 4];
      float4 b4 = *(const float4*)&Bs[kk][tx * 4];
      float a[4] = {a4.x, a4.y, a4.z, a4.w};
      float b[4] = {b4.x, b4.y, b4.z, b4.w};
      #pragma unroll
      for (int i = 0; i < 4; i++)
        #pragma unroll
        for (int j = 0; j < 4; j++) acc[i][j] += a[i] * b[j];
    }
    __syncthreads();
  }
  #pragma unroll
  for (int i = 0; i < 4; i++)
    #pragma unroll
    for (int j = 0; j < 4; j++) {
      size_t off = (size_t)(row0 + ty * 4 + i) * N + (col0 + tx * 4 + j);
      if (MODE == 1) C[off] += acc[i][j]; else C[off] = acc[i][j];
    }
}

// ---------------- FFN dual GEMM: act = silu(A@W1) * (A@W3) ----------------
__global__ __launch_bounds__(256) void k_ffn13(const float* __restrict__ A,
                                               const float* __restrict__ W1,
                                               const float* __restrict__ W3,
                                               float* __restrict__ act,
                                               int M, int N, int K) {
  __shared__ float As[16][64];
  __shared__ float B1s[16][64];
  __shared__ float B3s[16][64];
  int row0 = blockIdx.y * 64, col0 = blockIdx.x * 64;
  int tx = threadIdx.x & 15, ty = threadIdx.x >> 4;
  float acc1[4][4] = {}, acc2[4][4] = {};
  for (int k0 = 0; k0 < K; k0 += 16) {
    #pragma unroll
    for (int i = 0; i < 4; i++) {
      int idx = threadIdx.x + i * 256;
      int am = idx >> 4, ak = idx & 15;
      As[ak][am] = A[(size_t)(row0 + am) * K + (k0 + ak)];
      int bk = idx >> 6, bn = idx & 63;
      B1s[bk][bn] = W1[(size_t)(k0 + bk) * N + (col0 + bn)];
      B3s[bk][bn] = W3[(size_t)(k0 + bk) * N + (col0 + bn)];
    }
    __syncthreads();
    #pragma unroll
    for (int kk = 0; kk < 16; kk++) {
      float4 a4 = *(const float4*)&As[kk][ty * 4];
      float4 b4 = *(const float4*)&B1s[kk][tx * 4];
      float4 c4 = *(const float4*)&B3s[kk][tx * 4];
      float a[4] = {a4.x, a4.y, a4.z, a4.w};
      float b[4] = {b4.x, b4.y, b4.z, b4.w};
      float c[4] = {c4.x, c4.y, c4.z, c4.w};
      #pragma unroll
      for (int i = 0; i < 4; i++)
        #pragma unroll
        for (int j = 0; j < 4; j++) {
          acc1[i][j] += a[i] * b[j];
          acc2[i][j] += a[i] * c[j];
        }
    }
    __syncthreads();
  }
  #pragma unroll
  for (int i = 0; i < 4; i++)
    #pragma unroll
    for (int j = 0; j < 4; j++) {
      size_t off = (size_t)(row0 + ty * 4 + i) * N + (col0 + tx * 4 + j);
      float aa = acc1[i][j];
      float sg = 1.f / (1.f + expf(-aa));
      act[off] = aa * sg * acc2[i][j];
    }
}

// ---------------- RoPE (in-place on q and k) ----------------
__global__ void k_rope(float* __restrict__ q, float* __restrict__ k) {
  int idx = blockIdx.x * blockDim.x + threadIdx.x;  // kNS*kNH*kHALF threads
  if (idx >= kNS * kNH * kHALF) return;
  int d = idx & (kHALF - 1);
  int t = idx >> 5;
  int hh = t & (kNH - 1);
  int row = t >> 3;
  int s = row & (kS - 1);
  float freq = expf(-logf(10000.f) * ((float)d / (float)kHALF));
  float ang = (float)s * freq;
  float c = cosf(ang), sn = sinf(ang);
  size_t base = (size_t)row * kD + hh * kHD + d;
  float x1 = q[base], x2 = q[base + kHALF];
  q[base]         = x1 * c - x2 * sn;
  q[base + kHALF] = x1 * sn + x2 * c;
  x1 = k[base]; x2 = k[base + kHALF];
  k[base]         = x1 * c - x2 * sn;
  k[base + kHALF] = x1 * sn + x2 * c;
}

// ---------------- tiled causal flash attention ----------------
// block = 256 threads, handles (n, h, 64-row q-tile). K/V tiles of 64 in LDS.
// Qt/Kt stored transposed [d][row] (b128 reads broadcast / 2-way, free);
// Vs/Pt stored [row][dim] with stride 68 (b128 reads conflict-free, 272B rows aligned).
__global__ __launch_bounds__(256) void k_attn_tile(const float* __restrict__ q,
                                                   const float* __restrict__ k,
                                                   const float* __restrict__ v,
                                                   float* __restrict__ o) {
  int qt = blockIdx.x;                 // 0..7
  int nh = blockIdx.y;                 // 0..159
  int hh = nh & (kNH - 1), n = nh >> 3;
  int tid = threadIdx.x, tx = tid & 15, ty = tid >> 4;
  __shared__ float Qt[kHD][64];        // [d][q-row], pre-scaled
  __shared__ float Kt[kHD][64];        // [d][j-row]
  __shared__ float Vs[64][68];         // [j-row][d]
  __shared__ float Pt[64][68];         // [j-row][q-row]
  int q0 = qt * 64;

  #pragma unroll
  for (int it = 0; it < 4; it++) {
    int idx = tid + it * 256;
    int row = idx >> 4, c4 = idx & 15;
    float4 f = *(const float4*)(q + (((size_t)(n * kS + q0 + row) * kNH + hh) << 6) + c4 * 4);
    Qt[c4 * 4 + 0][row] = f.x * 0.125f;
    Qt[c4 * 4 + 1][row] = f.y * 0.125f;
    Qt[c4 * 4 + 2][row] = f.z * 0.125f;
    Qt[c4 * 4 + 3][row] = f.w * 0.125f;
  }
  float o_acc[4][4] = {};
  float m_run[4], l_run[4];
  #pragma unroll
  for (int i = 0; i < 4; i++) { m_run[i] = -1e30f; l_run[i] = 0.f; }

  for (int jt = 0; jt <= qt; jt++) {
    int j0 = jt * 64;
    __syncthreads();   // Qt ready (first iter) / prev PV done (later iters)
    #pragma unroll
    for (int it = 0; it < 4; it++) {
      int idx = tid + it * 256;
      int row = idx >> 4, c4 = idx & 15;
      size_t gb = (((size_t)(n * kS + j0 + row) * kNH + hh) << 6) + c4 * 4;
      float4 kf = *(const float4*)(k + gb);
      Kt[c4 * 4 + 0][row] = kf.x; Kt[c4 * 4 + 1][row] = kf.y;
      Kt[c4 * 4 + 2][row] = kf.z; Kt[c4 * 4 + 3][row] = kf.w;
      float4 vf = *(const float4*)(v + gb);
      Vs[row][c4 * 4 + 0] = vf.x; Vs[row][c4 * 4 + 1] = vf.y;
      Vs[row][c4 * 4 + 2] = vf.z; Vs[row][c4 * 4 + 3] = vf.w;
    }
    __syncthreads();

    // S = Q·K^T tile (rows 4ty.., cols 4tx..)
    float s_acc[4][4] = {};
    #pragma unroll 8
    for (int d = 0; d < kHD; d++) {
      float4 a4 = *(const float4*)&Qt[d][ty * 4];
      float4 b4 = *(const float4*)&Kt[d][tx * 4];
      float a[4] = {a4.x, a4.y, a4.z, a4.w};
      float b[4] = {b4.x, b4.y, b4.z, b4.w};
      #pragma unroll
      for (int i = 0; i < 4; i++)
        #pragma unroll
        for (int j = 0; j < 4; j++) s_acc[i][j] += a[i] * b[j];
    }
    if (jt == qt) {      // causal mask on the diagonal tile
      #pragma unroll
      for (int i = 0; i < 4; i++)
        #pragma unroll
        for (int j = 0; j < 4; j++)
          if (tx * 4 + j > ty * 4 + i) s_acc[i][j] = -1e30f;
    }

    // online softmax update (row stats across the 16-lane tx subgroup)
    float p[4][4], sc[4];
    #pragma unroll
    for (int i = 0; i < 4; i++) {
      float tm = fmaxf(fmaxf(s_acc[i][0], s_acc[i][1]), fmaxf(s_acc[i][2], s_acc[i][3]));
      #pragma unroll
      for (int off = 1; off < 16; off <<= 1) tm = fmaxf(tm, __shfl_xor(tm, off));
      float m_new = fmaxf(m_run[i], tm);
      sc[i] = expf(m_run[i] - m_new);
      float rs = 0.f;
      #pragma unroll
      for (int j = 0; j < 4; j++) { p[i][j] = expf(s_acc[i][j] - m_new); rs += p[i][j]; }
      #pragma unroll
      for (int off = 1; off < 16; off <<= 1) rs += __shfl_xor(rs, off);
      l_run[i] = l_run[i] * sc[i] + rs;
      m_run[i] = m_new;
    }
    #pragma unroll
    for (int i = 0; i < 4; i++)
      #pragma unroll
      for (int dd = 0; dd < 4; dd++) o_acc[i][dd] *= sc[i];

    // write P transposed: Pt[j][q]
    #pragma unroll
    for (int i = 0; i < 4; i++)
      #pragma unroll
      for (int j = 0; j < 4; j++) Pt[tx * 4 + j][ty * 4 + i] = p[i][j];
    __syncthreads();

    // O += P·V (rows 4ty.., dims 4tx..)
    #pragma unroll 8
    for (int j = 0; j < 64; j++) {
      float4 pv = *(const float4*)&Pt[j][ty * 4];
      float4 v4 = *(const float4*)&Vs[j][tx * 4];
      float pa[4] = {pv.x, pv.y, pv.z, pv.w};
      float vb[4] = {v4.x, v4.y, v4.z, v4.w};
      #pragma unroll
      for (int i = 0; i < 4; i++)
        #pragma unroll
        for (int dd = 0; dd < 4; dd++) o_acc[i][dd] += pa[i] * vb[dd];
    }
  }

  #pragma unroll
  for (int i = 0; i < 4; i++) {
    float inv = 1.f / l_run[i];
    float4 r;
    r.x = o_acc[i][0] * inv; r.y = o_acc[i][1] * inv;
    r.z = o_acc[i][2] * inv; r.w = o_acc[i][3] * inv;
    *(float4*)(o + (((size_t)(n * kS + q0 + ty * 4 + i) * kNH + hh) << 6) + tx * 4) = r;
  }
}

// ---------------- gather the 80 scoring rows (post final-norm) ----------------
__global__ void k_gather(const float* __restrict__ xn, float* __restrict__ hs) {
  int r = blockIdx.x;                       // 0..79 : r = n*LBL + li
  int n = r / kLBL, li = r - n * kLBL;
  size_t src = ((size_t)n * kS + (kT - 1 + li)) * kD;
  for (int i = threadIdx.x; i < kD; i += blockDim.x) hs[r * kD + i] = xn[src + i];
}

// ---------------- logits partials: per vocab-chunk (max, sumexp) for all 80 rows ----------------
__global__ __launch_bounds__(256) void k_logits_partial(const float* __restrict__ hs,
                                                        const float* __restrict__ lm,
                                                        float* __restrict__ part) {
  __shared__ float hss[kRG * kD];           // 40 KB, reused as reduce scratch
  int v = blockIdx.x * kVC + threadIdx.x;
  int tid = threadIdx.x, lane = tid & 63, wid = tid >> 6;
  for (int g = 0; g < 4; g++) {
    for (int i = tid; i < kRG * kD; i += 256) hss[i] = hs[g * kRG * kD + i];
    __syncthreads();
    float acc[kRG];
    #pragma unroll
    for (int r = 0; r < kRG; r++) acc[r] = 0.f;
    for (int d2 = 0; d2 < kD; d2++) {
      float wv = lm[(size_t)d2 * kV + v];
      #pragma unroll
      for (int r = 0; r < kRG; r++) acc[r] += hss[r * kD + d2] * wv;
    }
    __syncthreads();
    #pragma unroll
    for (int r = 0; r < kRG; r++) hss[r * 256 + tid] = acc[r];
    __syncthreads();
    for (int r = wid; r < kRG; r += 4) {
      float a0 = hss[r * 256 + lane],       a1 = hss[r * 256 + lane + 64];
      float a2 = hss[r * 256 + lane + 128], a3 = hss[r * 256 + lane + 192];
      float mx = fmaxf(fmaxf(a0, a1), fmaxf(a2, a3));
      #pragma unroll
      for (int o2 = 1; o2 < 64; o2 <<= 1) mx = fmaxf(mx, __shfl_xor(mx, o2));
      float se = expf(a0 - mx) + expf(a1 - mx) + expf(a2 - mx) + expf(a3 - mx);
      #pragma unroll
      for (int o2 = 1; o2 < 64; o2 <<= 1) se += __shfl_xor(se, o2);
      if (lane == 0) {
        size_t pi = ((size_t)(g * kRG + r) * kNChunk + blockIdx.x) * 2;
        part[pi] = mx; part[pi + 1] = se;
      }
    }
    __syncthreads();
  }
}

// ---------------- label-token logits ----------------
__global__ __launch_bounds__(64) void k_label_logits(const float* __restrict__ hs,
                                                     const float* __restrict__ lm,
                                                     const int* __restrict__ label_ids,
                                                     float* __restrict__ lbl) {
  int r = blockIdx.x;                       // 0..79
  int li = r & 3, n = r >> 2, lab = n / kB;
  int tok = label_ids[lab * kLBL + li];
  int lane = threadIdx.x;
  float dv = 0.f;
  for (int d2 = lane; d2 < kD; d2 += 64) dv += hs[r * kD + d2] * lm[(size_t)d2 * kV + tok];
  #pragma unroll
  for (int o2 = 1; o2 < 64; o2 <<= 1) dv += __shfl_xor(dv, o2);
  if (lane == 0) lbl[r] = dv;
}

// ---------------- final reduce: logsumexp combine + output ----------------
__global__ __launch_bounds__(64) void k_final(const float* __restrict__ part,
                                              const float* __restrict__ lbl,
                                              float* __restrict__ out) {
  int n = blockIdx.x;                       // 0..19, n = lab*B + b
  int lab = n / kB, b = n - lab * kB;
  int lane = threadIdx.x;
  float res = 0.f;
  for (int li = 0; li < kLBL; li++) {
    int r = n * kLBL + li;
    const float* pr = part + (size_t)r * kNChunk * 2;
    float mx = -1e30f;
    for (int c = lane; c < kNChunk; c += 64) mx = fmaxf(mx, pr[c * 2]);
    #pragma unroll
    for (int o2 = 1; o2 < 64; o2 <<= 1) mx = fmaxf(mx, __shfl_xor(mx, o2));
    float sum = 0.f;
    for (int c = lane; c < kNChunk; c += 64) sum += pr[c * 2 + 1] * expf(pr[c * 2] - mx);
    #pragma unroll
    for (int o2 = 1; o2 < 64; o2 <<= 1) sum += __shfl_xor(sum, o2);
    res += lbl[r] - (mx + logf(sum));
  }
  if (lane == 0) out[b * kNLAB + lab] = res;
}

extern "C" void kernel_launch(void* const* d_in, const int* in_sizes, int n_in,
                              void* d_out, int out_size, void* d_ws, size_t ws_size,
                              hipStream_t stream) {
  const int*   input_ids    = (const int*)d_in[0];
  const int*   label_ids    = (const int*)d_in[1];
  const float* emb          = (const float*)d_in[2];
  const float* wq           = (const float*)d_in[3];
  const float* wk           = (const float*)d_in[4];
  const float* wv           = (const float*)d_in[5];
  const float* wo           = (const float*)d_in[6];
  const float* w1           = (const float*)d_in[7];
  const float* w2           = (const float*)d_in[8];
  const float* w3           = (const float*)d_in[9];
  const float* attn_norm_w  = (const float*)d_in[10];
  const float* ffn_norm_w   = (const float*)d_in[11];
  const float* final_norm_w = (const float*)d_in[12];
  const float* lm_head      = (const float*)d_in[13];
  float* out = (float*)d_out;

  char* ws = (char*)d_ws;
  float* h    = (float*)(ws);                 // 20,971,520 B
  float* xn   = (float*)(ws + 20971520);      // 20,971,520
  float* q    = (float*)(ws + 41943040);      // 20,971,520
  float* kk   = (float*)(ws + 62914560);      // 20,971,520
  float* vv   = (float*)(ws + 83886080);      // 20,971,520
  float* big  = (float*)(ws + 104857600);     // 57,671,680 (attn-out / ffn act)
  float* hs   = (float*)(ws + 162529280);     // 163,840
  float* part = (float*)(ws + 162693120);     // 320,000
  float* lbl  = (float*)(ws + 163013120);     // 320

  k_embed<<<kNS, 128, 0, stream>>>(input_ids, label_ids, emb, h);

  for (int l = 0; l < kNL; l++) {
    k_rmsnorm<<<kNS, 256, 0, stream>>>(h, attn_norm_w + (size_t)l * kD, xn);
    dim3 gqkv(kD / 64, kNS / 64);
    k_gemm<0><<<gqkv, 256, 0, stream>>>(xn, wq + (size_t)l * kD * kD, q,  kNS, kD, kD);
    k_gemm<0><<<gqkv, 256, 0, stream>>>(xn, wk + (size_t)l * kD * kD, kk, kNS, kD, kD);
    k_gemm<0><<<gqkv, 256, 0, stream>>>(xn, wv + (size_t)l * kD * kD, vv, kNS, kD, kD);
    k_rope<<<(kNS * kNH * kHALF) / 256, 256, 0, stream>>>(q, kk);
    dim3 gattn(kS / 64, kNSeq * kNH);
    k_attn_tile<<<gattn, 256, 0, stream>>>(q, kk, vv, big);
    k_gemm<1><<<gqkv, 256, 0, stream>>>(big, wo + (size_t)l * kD * kD, h, kNS, kD, kD);
    k_rmsnorm<<<kNS, 256, 0, stream>>>(h, ffn_norm_w + (size_t)l * kD, xn);
    dim3 gffn(kHID / 64, kNS / 64);
    k_ffn13<<<gffn, 256, 0, stream>>>(xn, w1 + (size_t)l * kD * kHID,
                                      w3 + (size_t)l * kD * kHID, big, kNS, kHID, kD);
    dim3 gw2(kD / 64, kNS / 64);
    k_gemm<1><<<gw2, 256, 0, stream>>>(big, w2 + (size_t)l * kHID * kD, h, kNS, kD, kHID);
  }

  k_rmsnorm<<<kNS, 256, 0, stream>>>(h, final_norm_w, xn);
  k_gather<<<kNSeq * kLBL, 128, 0, stream>>>(xn, hs);
  k_logits_partial<<<kNChunk, 256, 0, stream>>>(hs, lm_head, part);
  k_label_logits<<<kNSeq * kLBL, 64, 0, stream>>>(hs, lm_head, label_ids, lbl);
  k_final<<<kNSeq, 64, 0, stream>>>(part, lbl, out);
}

// Round 3
// 1337.794 us; speedup vs baseline: 3.2745x; 2.2634x over previous
//
#include <hip/hip_runtime.h>
#include <math.h>

namespace {
constexpr int kV = 128000, kD = 512, kNH = 8, kNL = 2, kHID = 1408;
constexpr int kHD = 64, kHALF = 32, kB = 4, kT = 508, kNLAB = 5, kLBL = 4;
constexpr int kS = 512;                 // T + LBL
constexpr int kNSeq = kNLAB * kB;       // 20
constexpr int kNS = kNSeq * kS;         // 10240 rows
constexpr float kEps = 1e-5f;
constexpr int kNChunk = 2000;           // 64-col partial chunks (128000/64)
constexpr int kPad = 56;                // LDS row stride in bf16 (112B: 16B-aligned, 2-way banks)
}

typedef __attribute__((ext_vector_type(8))) short bf16x8;
typedef __attribute__((ext_vector_type(4))) float f32x4;

__device__ inline uint32_t pk2(float lo, float hi) {   // RNE fp32->bf16 pair, hi<<16|lo
  uint32_t ul = __builtin_bit_cast(uint32_t, lo);
  uint32_t uh = __builtin_bit_cast(uint32_t, hi);
  ul += 0x7fffu + ((ul >> 16) & 1u);
  uh += 0x7fffu + ((uh >> 16) & 1u);
  return (ul >> 16) | (uh & 0xffff0000u);
}

// ---------------- embedding ----------------
__global__ void k_embed(const int* __restrict__ input_ids, const int* __restrict__ label_ids,
                        const float* __restrict__ emb, float* __restrict__ h) {
  int row = blockIdx.x;
  int n = row / kS, s = row - n * kS;
  int lab = n / kB, b = n - lab * kB;
  int tok = (s < kT) ? input_ids[b * kT + s] : label_ids[lab * kLBL + (s - kT)];
  const float4* src = (const float4*)(emb + (size_t)tok * kD);
  float4* dst = (float4*)(h + (size_t)row * kD);
  for (int i = threadIdx.x; i < kD / 4; i += blockDim.x) dst[i] = src[i];
}

// ---------------- rmsnorm ----------------
__global__ __launch_bounds__(256) void k_rmsnorm(const float* __restrict__ x,
                                                 const float* __restrict__ w,
                                                 float* __restrict__ y) {
  int row = blockIdx.x;
  const float* xr = x + (size_t)row * kD;
  float ss = 0.f;
  for (int i = threadIdx.x; i < kD; i += 256) { float v = xr[i]; ss += v * v; }
  #pragma unroll
  for (int o = 1; o < 64; o <<= 1) ss += __shfl_xor(ss, o);
  __shared__ float wsum[4];
  int lane = threadIdx.x & 63, wid = threadIdx.x >> 6;
  if (lane == 0) wsum[wid] = ss;
  __syncthreads();
  float tot = wsum[0] + wsum[1] + wsum[2] + wsum[3];
  float inv = rsqrtf(tot / (float)kD + kEps);
  for (int i = threadIdx.x; i < kD; i += 256)
    y[(size_t)row * kD + i] = xr[i] * inv * w[i];
}

// ---------------- bf16 MFMA GEMM: C[M,N] (+)= A[M,K] @ B[K,N], fp32 in/out ----------------
// 128x128 tile, 256 threads (4 waves 2x2), K-step 32, fp32->bf16 during staging.
template<int MODE>  // 0: C=A@B   1: C+=A@B
__global__ __launch_bounds__(256) void k_gemm_bf16(const float* __restrict__ A,
                                                   const float* __restrict__ Bsrc,
                                                   float* __restrict__ C,
                                                   int M, int N, int K) {
  __shared__ short As[128 * kPad];
  __shared__ short Bs[128 * kPad];
  int row0 = blockIdx.y * 128, col0 = blockIdx.x * 128;
  int tid = threadIdx.x;
  int wave = tid >> 6, lane = tid & 63;
  int wm = wave >> 1, wn = wave & 1;
  int l15 = lane & 15, l16 = lane >> 4;
  f32x4 acc[4][4];
  #pragma unroll
  for (int i = 0; i < 4; i++)
    #pragma unroll
    for (int j = 0; j < 4; j++) acc[i][j] = (f32x4){0.f, 0.f, 0.f, 0.f};

  int arow = tid >> 1, ahalf = tid & 1;     // A staging: row, 16-float k-half
  int bkp = tid >> 4, bf4 = tid & 15;       // B staging: k-pair, float4-col

  for (int k0 = 0; k0 < K; k0 += 32) {
    // ---- stage A tile [128][32] -> As[row][k] bf16 ----
    {
      const float* ag = A + (size_t)(row0 + arow) * K + k0 + ahalf * 16;
      float4 a0 = *(const float4*)(ag + 0), a1 = *(const float4*)(ag + 4);
      float4 a2 = *(const float4*)(ag + 8), a3 = *(const float4*)(ag + 12);
      uint4 u0 = { pk2(a0.x, a0.y), pk2(a0.z, a0.w), pk2(a1.x, a1.y), pk2(a1.z, a1.w) };
      uint4 u1 = { pk2(a2.x, a2.y), pk2(a2.z, a2.w), pk2(a3.x, a3.y), pk2(a3.z, a3.w) };
      *(uint4*)&As[arow * kPad + ahalf * 16] = u0;
      *(uint4*)&As[arow * kPad + ahalf * 16 + 8] = u1;
    }
    // ---- stage B tile [32][128] -> Bs[col][k] bf16 (transposed) ----
    #pragma unroll
    for (int t = 0; t < 2; t++) {
      int colq = bf4 + 16 * t;
      const float* bg = Bsrc + (size_t)(k0 + 2 * bkp) * N + col0 + colq * 4;
      float4 lo = *(const float4*)bg;
      float4 hi = *(const float4*)(bg + N);
      *(uint32_t*)&Bs[(colq * 4 + 0) * kPad + 2 * bkp] = pk2(lo.x, hi.x);
      *(uint32_t*)&Bs[(colq * 4 + 1) * kPad + 2 * bkp] = pk2(lo.y, hi.y);
      *(uint32_t*)&Bs[(colq * 4 + 2) * kPad + 2 * bkp] = pk2(lo.z, hi.z);
      *(uint32_t*)&Bs[(colq * 4 + 3) * kPad + 2 * bkp] = pk2(lo.w, hi.w);
    }
    __syncthreads();
    bf16x8 af[4], bfr[4];
    #pragma unroll
    for (int mf = 0; mf < 4; mf++)
      af[mf] = *(const bf16x8*)&As[(wm * 64 + mf * 16 + l15) * kPad + l16 * 8];
    #pragma unroll
    for (int nf = 0; nf < 4; nf++)
      bfr[nf] = *(const bf16x8*)&Bs[(wn * 64 + nf * 16 + l15) * kPad + l16 * 8];
    #pragma unroll
    for (int mf = 0; mf < 4; mf++)
      #pragma unroll
      for (int nf = 0; nf < 4; nf++)
        acc[mf][nf] = __builtin_amdgcn_mfma_f32_16x16x32_bf16(af[mf], bfr[nf], acc[mf][nf], 0, 0, 0);
    __syncthreads();
  }
  #pragma unroll
  for (int mf = 0; mf < 4; mf++)
    #pragma unroll
    for (int nf = 0; nf < 4; nf++)
      #pragma unroll
      for (int r = 0; r < 4; r++) {
        int row = row0 + wm * 64 + mf * 16 + l16 * 4 + r;
        int col = col0 + wn * 64 + nf * 16 + l15;
        size_t off = (size_t)row * N + col;
        if (MODE == 1) C[off] += acc[mf][nf][r]; else C[off] = acc[mf][nf][r];
      }
}

// ---------------- FFN dual GEMM via MFMA: act = silu(A@W1) * (A@W3) ----------------
__global__ __launch_bounds__(256) void k_ffn13_bf16(const float* __restrict__ A,
                                                    const float* __restrict__ W1,
                                                    const float* __restrict__ W3,
                                                    float* __restrict__ act,
                                                    int M, int N, int K) {
  __shared__ short As[128 * kPad];
  __shared__ short B1[128 * kPad];
  __shared__ short B2[128 * kPad];
  int row0 = blockIdx.y * 128, col0 = blockIdx.x * 128;
  int tid = threadIdx.x;
  int wave = tid >> 6, lane = tid & 63;
  int wm = wave >> 1, wn = wave & 1;
  int l15 = lane & 15, l16 = lane >> 4;
  f32x4 acc1[4][4], acc2[4][4];
  #pragma unroll
  for (int i = 0; i < 4; i++)
    #pragma unroll
    for (int j = 0; j < 4; j++) {
      acc1[i][j] = (f32x4){0.f, 0.f, 0.f, 0.f};
      acc2[i][j] = (f32x4){0.f, 0.f, 0.f, 0.f};
    }
  int arow = tid >> 1, ahalf = tid & 1;
  int bkp = tid >> 4, bf4 = tid & 15;

  for (int k0 = 0; k0 < K; k0 += 32) {
    {
      const float* ag = A + (size_t)(row0 + arow) * K + k0 + ahalf * 16;
      float4 a0 = *(const float4*)(ag + 0), a1 = *(const float4*)(ag + 4);
      float4 a2 = *(const float4*)(ag + 8), a3 = *(const float4*)(ag + 12);
      uint4 u0 = { pk2(a0.x, a0.y), pk2(a0.z, a0.w), pk2(a1.x, a1.y), pk2(a1.z, a1.w) };
      uint4 u1 = { pk2(a2.x, a2.y), pk2(a2.z, a2.w), pk2(a3.x, a3.y), pk2(a3.z, a3.w) };
      *(uint4*)&As[arow * kPad + ahalf * 16] = u0;
      *(uint4*)&As[arow * kPad + ahalf * 16 + 8] = u1;
    }
    #pragma unroll
    for (int t = 0; t < 2; t++) {
      int colq = bf4 + 16 * t;
      const float* bg1 = W1 + (size_t)(k0 + 2 * bkp) * N + col0 + colq * 4;
      float4 lo = *(const float4*)bg1;
      float4 hi = *(const float4*)(bg1 + N);
      *(uint32_t*)&B1[(colq * 4 + 0) * kPad + 2 * bkp] = pk2(lo.x, hi.x);
      *(uint32_t*)&B1[(colq * 4 + 1) * kPad + 2 * bkp] = pk2(lo.y, hi.y);
      *(uint32_t*)&B1[(colq * 4 + 2) * kPad + 2 * bkp] = pk2(lo.z, hi.z);
      *(uint32_t*)&B1[(colq * 4 + 3) * kPad + 2 * bkp] = pk2(lo.w, hi.w);
      const float* bg3 = W3 + (size_t)(k0 + 2 * bkp) * N + col0 + colq * 4;
      float4 lo3 = *(const float4*)bg3;
      float4 hi3 = *(const float4*)(bg3 + N);
      *(uint32_t*)&B2[(colq * 4 + 0) * kPad + 2 * bkp] = pk2(lo3.x, hi3.x);
      *(uint32_t*)&B2[(colq * 4 + 1) * kPad + 2 * bkp] = pk2(lo3.y, hi3.y);
      *(uint32_t*)&B2[(colq * 4 + 2) * kPad + 2 * bkp] = pk2(lo3.z, hi3.z);
      *(uint32_t*)&B2[(colq * 4 + 3) * kPad + 2 * bkp] = pk2(lo3.w, hi3.w);
    }
    __syncthreads();
    bf16x8 af[4], b1f[4], b2f[4];
    #pragma unroll
    for (int mf = 0; mf < 4; mf++)
      af[mf] = *(const bf16x8*)&As[(wm * 64 + mf * 16 + l15) * kPad + l16 * 8];
    #pragma unroll
    for (int nf = 0; nf < 4; nf++) {
      b1f[nf] = *(const bf16x8*)&B1[(wn * 64 + nf * 16 + l15) * kPad + l16 * 8];
      b2f[nf] = *(const bf16x8*)&B2[(wn * 64 + nf * 16 + l15) * kPad + l16 * 8];
    }
    #pragma unroll
    for (int mf = 0; mf < 4; mf++)
      #pragma unroll
      for (int nf = 0; nf < 4; nf++) {
        acc1[mf][nf] = __builtin_amdgcn_mfma_f32_16x16x32_bf16(af[mf], b1f[nf], acc1[mf][nf], 0, 0, 0);
        acc2[mf][nf] = __builtin_amdgcn_mfma_f32_16x16x32_bf16(af[mf], b2f[nf], acc2[mf][nf], 0, 0, 0);
      }
    __syncthreads();
  }
  #pragma unroll
  for (int mf = 0; mf < 4; mf++)
    #pragma unroll
    for (int nf = 0; nf < 4; nf++)
      #pragma unroll
      for (int r = 0; r < 4; r++) {
        int row = row0 + wm * 64 + mf * 16 + l16 * 4 + r;
        int col = col0 + wn * 64 + nf * 16 + l15;
        float aa = acc1[mf][nf][r];
        float sg = 1.f / (1.f + expf(-aa));
        act[(size_t)row * N + col] = aa * sg * acc2[mf][nf][r];
      }
}

// ---------------- RoPE ----------------
__global__ void k_rope(float* __restrict__ q, float* __restrict__ k) {
  int idx = blockIdx.x * blockDim.x + threadIdx.x;
  if (idx >= kNS * kNH * kHALF) return;
  int d = idx & (kHALF - 1);
  int t = idx >> 5;
  int hh = t & (kNH - 1);
  int row = t >> 3;
  int s = row & (kS - 1);
  float freq = expf(-logf(10000.f) * ((float)d / (float)kHALF));
  float ang = (float)s * freq;
  float c = cosf(ang), sn = sinf(ang);
  size_t base = (size_t)row * kD + hh * kHD + d;
  float x1 = q[base], x2 = q[base + kHALF];
  q[base]         = x1 * c - x2 * sn;
  q[base + kHALF] = x1 * sn + x2 * c;
  x1 = k[base]; x2 = k[base + kHALF];
  k[base]         = x1 * c - x2 * sn;
  k[base + kHALF] = x1 * sn + x2 * c;
}

// ---------------- tiled causal flash attention (fp32 VALU) ----------------
__global__ __launch_bounds__(256) void k_attn_tile(const float* __restrict__ q,
                                                   const float* __restrict__ k,
                                                   const float* __restrict__ v,
                                                   float* __restrict__ o) {
  int qt = blockIdx.x;
  int nh = blockIdx.y;
  int hh = nh & (kNH - 1), n = nh >> 3;
  int tid = threadIdx.x, tx = tid & 15, ty = tid >> 4;
  __shared__ float Qt[kHD][64];
  __shared__ float Kt[kHD][64];
  __shared__ float Vs[64][68];
  __shared__ float Pt[64][68];
  int q0 = qt * 64;

  #pragma unroll
  for (int it = 0; it < 4; it++) {
    int idx = tid + it * 256;
    int row = idx >> 4, c4 = idx & 15;
    float4 f = *(const float4*)(q + (((size_t)(n * kS + q0 + row) * kNH + hh) << 6) + c4 * 4);
    Qt[c4 * 4 + 0][row] = f.x * 0.125f;
    Qt[c4 * 4 + 1][row] = f.y * 0.125f;
    Qt[c4 * 4 + 2][row] = f.z * 0.125f;
    Qt[c4 * 4 + 3][row] = f.w * 0.125f;
  }
  float o_acc[4][4] = {};
  float m_run[4], l_run[4];
  #pragma unroll
  for (int i = 0; i < 4; i++) { m_run[i] = -1e30f; l_run[i] = 0.f; }

  for (int jt = 0; jt <= qt; jt++) {
    int j0 = jt * 64;
    __syncthreads();
    #pragma unroll
    for (int it = 0; it < 4; it++) {
      int idx = tid + it * 256;
      int row = idx >> 4, c4 = idx & 15;
      size_t gb = (((size_t)(n * kS + j0 + row) * kNH + hh) << 6) + c4 * 4;
      float4 kf = *(const float4*)(k + gb);
      Kt[c4 * 4 + 0][row] = kf.x; Kt[c4 * 4 + 1][row] = kf.y;
      Kt[c4 * 4 + 2][row] = kf.z; Kt[c4 * 4 + 3][row] = kf.w;
      float4 vf = *(const float4*)(v + gb);
      Vs[row][c4 * 4 + 0] = vf.x; Vs[row][c4 * 4 + 1] = vf.y;
      Vs[row][c4 * 4 + 2] = vf.z; Vs[row][c4 * 4 + 3] = vf.w;
    }
    __syncthreads();

    float s_acc[4][4] = {};
    #pragma unroll 8
    for (int d = 0; d < kHD; d++) {
      float4 a4 = *(const float4*)&Qt[d][ty * 4];
      float4 b4 = *(const float4*)&Kt[d][tx * 4];
      float a[4] = {a4.x, a4.y, a4.z, a4.w};
      float b[4] = {b4.x, b4.y, b4.z, b4.w};
      #pragma unroll
      for (int i = 0; i < 4; i++)
        #pragma unroll
        for (int j = 0; j < 4; j++) s_acc[i][j] += a[i] * b[j];
    }
    if (jt == qt) {
      #pragma unroll
      for (int i = 0; i < 4; i++)
        #pragma unroll
        for (int j = 0; j < 4; j++)
          if (tx * 4 + j > ty * 4 + i) s_acc[i][j] = -1e30f;
    }

    float p[4][4], sc[4];
    #pragma unroll
    for (int i = 0; i < 4; i++) {
      float tm = fmaxf(fmaxf(s_acc[i][0], s_acc[i][1]), fmaxf(s_acc[i][2], s_acc[i][3]));
      #pragma unroll
      for (int off = 1; off < 16; off <<= 1) tm = fmaxf(tm, __shfl_xor(tm, off));
      float m_new = fmaxf(m_run[i], tm);
      sc[i] = expf(m_run[i] - m_new);
      float rs = 0.f;
      #pragma unroll
      for (int j = 0; j < 4; j++) { p[i][j] = expf(s_acc[i][j] - m_new); rs += p[i][j]; }
      #pragma unroll
      for (int off = 1; off < 16; off <<= 1) rs += __shfl_xor(rs, off);
      l_run[i] = l_run[i] * sc[i] + rs;
      m_run[i] = m_new;
    }
    #pragma unroll
    for (int i = 0; i < 4; i++)
      #pragma unroll
      for (int dd = 0; dd < 4; dd++) o_acc[i][dd] *= sc[i];

    #pragma unroll
    for (int i = 0; i < 4; i++)
      #pragma unroll
      for (int j = 0; j < 4; j++) Pt[tx * 4 + j][ty * 4 + i] = p[i][j];
    __syncthreads();

    #pragma unroll 8
    for (int j = 0; j < 64; j++) {
      float4 pv = *(const float4*)&Pt[j][ty * 4];
      float4 v4 = *(const float4*)&Vs[j][tx * 4];
      float pa[4] = {pv.x, pv.y, pv.z, pv.w};
      float vb[4] = {v4.x, v4.y, v4.z, v4.w};
      #pragma unroll
      for (int i = 0; i < 4; i++)
        #pragma unroll
        for (int dd = 0; dd < 4; dd++) o_acc[i][dd] += pa[i] * vb[dd];
    }
  }

  #pragma unroll
  for (int i = 0; i < 4; i++) {
    float inv = 1.f / l_run[i];
    float4 r;
    r.x = o_acc[i][0] * inv; r.y = o_acc[i][1] * inv;
    r.z = o_acc[i][2] * inv; r.w = o_acc[i][3] * inv;
    *(float4*)(o + (((size_t)(n * kS + q0 + ty * 4 + i) * kNH + hh) << 6) + tx * 4) = r;
  }
}

// ---------------- gather the 80 scoring rows ----------------
__global__ void k_gather(const float* __restrict__ xn, float* __restrict__ hs) {
  int r = blockIdx.x;
  int n = r / kLBL, li = r - n * kLBL;
  size_t src = ((size_t)n * kS + (kT - 1 + li)) * kD;
  for (int i = threadIdx.x; i < kD; i += blockDim.x) hs[r * kD + i] = xn[src + i];
}

// ---------------- logits partials via MFMA: one pass over lm_head ----------------
// block: 256 cols, M=80, K=512. wave w covers cols [blk*256 + w*64, +64).
// writes per-row (max, sumexp) partials at 64-col granularity (2000 chunks).
__global__ __launch_bounds__(256) void k_logits_mfma(const float* __restrict__ hs,
                                                     const float* __restrict__ lm,
                                                     float* __restrict__ part) {
  __shared__ short As[80 * kPad];
  __shared__ short Bs[256 * kPad];
  int tid = threadIdx.x;
  int wave = tid >> 6, lane = tid & 63;
  int l15 = lane & 15, l16 = lane >> 4;
  int col0 = blockIdx.x * 256;
  f32x4 acc[5][4];
  #pragma unroll
  for (int i = 0; i < 5; i++)
    #pragma unroll
    for (int j = 0; j < 4; j++) acc[i][j] = (f32x4){0.f, 0.f, 0.f, 0.f};

  int arow = tid >> 1, ahalf = tid & 1;
  int bkp = tid >> 4, bf4 = tid & 15;

  for (int k0 = 0; k0 < kD; k0 += 32) {
    if (tid < 160) {
      const float* ag = hs + (size_t)arow * kD + k0 + ahalf * 16;
      float4 a0 = *(const float4*)(ag + 0), a1 = *(const float4*)(ag + 4);
      float4 a2 = *(const float4*)(ag + 8), a3 = *(const float4*)(ag + 12);
      uint4 u0 = { pk2(a0.x, a0.y), pk2(a0.z, a0.w), pk2(a1.x, a1.y), pk2(a1.z, a1.w) };
      uint4 u1 = { pk2(a2.x, a2.y), pk2(a2.z, a2.w), pk2(a3.x, a3.y), pk2(a3.z, a3.w) };
      *(uint4*)&As[arow * kPad + ahalf * 16] = u0;
      *(uint4*)&As[arow * kPad + ahalf * 16 + 8] = u1;
    }
    #pragma unroll
    for (int t = 0; t < 4; t++) {
      int colq = bf4 + 16 * t;                      // float4-col 0..63
      const float* bg = lm + (size_t)(k0 + 2 * bkp) * kV + col0 + colq * 4;
      float4 lo = *(const float4*)bg;
      float4 hi = *(const float4*)(bg + kV);
      *(uint32_t*)&Bs[(colq * 4 + 0) * kPad + 2 * bkp] = pk2(lo.x, hi.x);
      *(uint32_t*)&Bs[(colq * 4 + 1) * kPad + 2 * bkp] = pk2(lo.y, hi.y);
      *(uint32_t*)&Bs[(colq * 4 + 2) * kPad + 2 * bkp] = pk2(lo.z, hi.z);
      *(uint32_t*)&Bs[(colq * 4 + 3) * kPad + 2 * bkp] = pk2(lo.w, hi.w);
    }
    __syncthreads();
    bf16x8 af[5], bfr[4];
    #pragma unroll
    for (int mf = 0; mf < 5; mf++)
      af[mf] = *(const bf16x8*)&As[(mf * 16 + l15) * kPad + l16 * 8];
    #pragma unroll
    for (int nf = 0; nf < 4; nf++)
      bfr[nf] = *(const bf16x8*)&Bs[(wave * 64 + nf * 16 + l15) * kPad + l16 * 8];
    #pragma unroll
    for (int mf = 0; mf < 5; mf++)
      #pragma unroll
      for (int nf = 0; nf < 4; nf++)
        acc[mf][nf] = __builtin_amdgcn_mfma_f32_16x16x32_bf16(af[mf], bfr[nf], acc[mf][nf], 0, 0, 0);
    __syncthreads();
  }

  // per-row (max, sumexp) over this wave's 64 cols
  int chunk = blockIdx.x * 4 + wave;
  #pragma unroll
  for (int mf = 0; mf < 5; mf++)
    #pragma unroll
    for (int r = 0; r < 4; r++) {
      float mx = fmaxf(fmaxf(acc[mf][0][r], acc[mf][1][r]),
                       fmaxf(acc[mf][2][r], acc[mf][3][r]));
      #pragma unroll
      for (int off = 1; off < 16; off <<= 1) mx = fmaxf(mx, __shfl_xor(mx, off));
      float se = expf(acc[mf][0][r] - mx) + expf(acc[mf][1][r] - mx) +
                 expf(acc[mf][2][r] - mx) + expf(acc[mf][3][r] - mx);
      #pragma unroll
      for (int off = 1; off < 16; off <<= 1) se += __shfl_xor(se, off);
      if (l15 == 0) {
        int row = mf * 16 + l16 * 4 + r;
        size_t pi = ((size_t)row * kNChunk + chunk) * 2;
        part[pi] = mx; part[pi + 1] = se;
      }
    }
}

// ---------------- label-token logits ----------------
__global__ __launch_bounds__(64) void k_label_logits(const float* __restrict__ hs,
                                                     const float* __restrict__ lm,
                                                     const int* __restrict__ label_ids,
                                                     float* __restrict__ lbl) {
  int r = blockIdx.x;
  int li = r & 3, n = r >> 2, lab = n / kB;
  int tok = label_ids[lab * kLBL + li];
  int lane = threadIdx.x;
  float dv = 0.f;
  for (int d2 = lane; d2 < kD; d2 += 64) dv += hs[r * kD + d2] * lm[(size_t)d2 * kV + tok];
  #pragma unroll
  for (int o2 = 1; o2 < 64; o2 <<= 1) dv += __shfl_xor(dv, o2);
  if (lane == 0) lbl[r] = dv;
}

// ---------------- final reduce ----------------
__global__ __launch_bounds__(64) void k_final(const float* __restrict__ part,
                                              const float* __restrict__ lbl,
                                              float* __restrict__ out) {
  int n = blockIdx.x;
  int lab = n / kB, b = n - lab * kB;
  int lane = threadIdx.x;
  float res = 0.f;
  for (int li = 0; li < kLBL; li++) {
    int r = n * kLBL + li;
    const float* pr = part + (size_t)r * kNChunk * 2;
    float mx = -1e30f;
    for (int c = lane; c < kNChunk; c += 64) mx = fmaxf(mx, pr[c * 2]);
    #pragma unroll
    for (int o2 = 1; o2 < 64; o2 <<= 1) mx = fmaxf(mx, __shfl_xor(mx, o2));
    float sum = 0.f;
    for (int c = lane; c < kNChunk; c += 64) sum += pr[c * 2 + 1] * expf(pr[c * 2] - mx);
    #pragma unroll
    for (int o2 = 1; o2 < 64; o2 <<= 1) sum += __shfl_xor(sum, o2);
    res += lbl[r] - (mx + logf(sum));
  }
  if (lane == 0) out[b * kNLAB + lab] = res;
}

extern "C" void kernel_launch(void* const* d_in, const int* in_sizes, int n_in,
                              void* d_out, int out_size, void* d_ws, size_t ws_size,
                              hipStream_t stream) {
  const int*   input_ids    = (const int*)d_in[0];
  const int*   label_ids    = (const int*)d_in[1];
  const float* emb          = (const float*)d_in[2];
  const float* wq           = (const float*)d_in[3];
  const float* wk           = (const float*)d_in[4];
  const float* wv           = (const float*)d_in[5];
  const float* wo           = (const float*)d_in[6];
  const float* w1           = (const float*)d_in[7];
  const float* w2           = (const float*)d_in[8];
  const float* w3           = (const float*)d_in[9];
  const float* attn_norm_w  = (const float*)d_in[10];
  const float* ffn_norm_w   = (const float*)d_in[11];
  const float* final_norm_w = (const float*)d_in[12];
  const float* lm_head      = (const float*)d_in[13];
  float* out = (float*)d_out;

  char* ws = (char*)d_ws;
  float* h    = (float*)(ws);                 // 20,971,520 B
  float* xn   = (float*)(ws + 20971520);      // 20,971,520
  float* q    = (float*)(ws + 41943040);      // 20,971,520
  float* kk   = (float*)(ws + 62914560);      // 20,971,520
  float* vv   = (float*)(ws + 83886080);      // 20,971,520
  float* big  = (float*)(ws + 104857600);     // 57,671,680 (attn-out / ffn act)
  float* hs   = (float*)(ws + 162529280);     // 163,840
  float* part = (float*)(ws + 162693120);     // 1,280,000
  float* lbl  = (float*)(ws + 163973120);     // 320

  k_embed<<<kNS, 128, 0, stream>>>(input_ids, label_ids, emb, h);

  for (int l = 0; l < kNL; l++) {
    k_rmsnorm<<<kNS, 256, 0, stream>>>(h, attn_norm_w + (size_t)l * kD, xn);
    dim3 gqkv(kD / 128, kNS / 128);
    k_gemm_bf16<0><<<gqkv, 256, 0, stream>>>(xn, wq + (size_t)l * kD * kD, q,  kNS, kD, kD);
    k_gemm_bf16<0><<<gqkv, 256, 0, stream>>>(xn, wk + (size_t)l * kD * kD, kk, kNS, kD, kD);
    k_gemm_bf16<0><<<gqkv, 256, 0, stream>>>(xn, wv + (size_t)l * kD * kD, vv, kNS, kD, kD);
    k_rope<<<(kNS * kNH * kHALF) / 256, 256, 0, stream>>>(q, kk);
    dim3 gattn(kS / 64, kNSeq * kNH);
    k_attn_tile<<<gattn, 256, 0, stream>>>(q, kk, vv, big);
    k_gemm_bf16<1><<<gqkv, 256, 0, stream>>>(big, wo + (size_t)l * kD * kD, h, kNS, kD, kD);
    k_rmsnorm<<<kNS, 256, 0, stream>>>(h, ffn_norm_w + (size_t)l * kD, xn);
    dim3 gffn(kHID / 128, kNS / 128);
    k_ffn13_bf16<<<gffn, 256, 0, stream>>>(xn, w1 + (size_t)l * kD * kHID,
                                           w3 + (size_t)l * kD * kHID, big, kNS, kHID, kD);
    dim3 gw2(kD / 128, kNS / 128);
    k_gemm_bf16<1><<<gw2, 256, 0, stream>>>(big, w2 + (size_t)l * kHID * kD, h, kNS, kD, kHID);
  }

  k_rmsnorm<<<kNS, 256, 0, stream>>>(h, final_norm_w, xn);
  k_gather<<<kNSeq * kLBL, 128, 0, stream>>>(xn, hs);
  k_logits_mfma<<<kV / 256, 256, 0, stream>>>(hs, lm_head, part);
  k_label_logits<<<kNSeq * kLBL, 64, 0, stream>>>(hs, lm_head, label_ids, lbl);
  k_final<<<kNSeq, 64, 0, stream>>>(part, lbl, out);
}

// Round 4
// 1063.180 us; speedup vs baseline: 4.1203x; 1.2583x over previous
//
#include <hip/hip_runtime.h>
#include <math.h>

namespace {
constexpr int kV = 128000, kD = 512, kNH = 8, kNL = 2, kHID = 1408;
constexpr int kHD = 64, kHALF = 32, kB = 4, kT = 508, kNLAB = 5, kLBL = 4;
constexpr int kS = 512;                 // T + LBL
constexpr int kNSeq = kNLAB * kB;       // 20
constexpr int kNS = kNSeq * kS;         // 10240 rows
constexpr float kEps = 1e-5f;
constexpr int kNChunk = 2000;           // 64-col partial chunks (128000/64)
constexpr int kPad = 56;                // LDS row stride in bf16 (112B)
constexpr int kStr = 72;                // attn LDS row stride in bf16 (144B, 16B-aligned)
}

typedef __attribute__((ext_vector_type(8))) short bf16x8;
typedef __attribute__((ext_vector_type(4))) float f32x4;

__device__ inline uint32_t pk2(float lo, float hi) {   // RNE fp32->bf16 pair, hi<<16|lo
  uint32_t ul = __builtin_bit_cast(uint32_t, lo);
  uint32_t uh = __builtin_bit_cast(uint32_t, hi);
  ul += 0x7fffu + ((ul >> 16) & 1u);
  uh += 0x7fffu + ((uh >> 16) & 1u);
  return (ul >> 16) | (uh & 0xffff0000u);
}
__device__ inline short bf1(float x) {
  uint32_t u = __builtin_bit_cast(uint32_t, x);
  u += 0x7fffu + ((u >> 16) & 1u);
  return (short)(u >> 16);
}

// ---------------- embedding ----------------
__global__ void k_embed(const int* __restrict__ input_ids, const int* __restrict__ label_ids,
                        const float* __restrict__ emb, float* __restrict__ h) {
  int row = blockIdx.x;
  int n = row / kS, s = row - n * kS;
  int lab = n / kB, b = n - lab * kB;
  int tok = (s < kT) ? input_ids[b * kT + s] : label_ids[lab * kLBL + (s - kT)];
  const float4* src = (const float4*)(emb + (size_t)tok * kD);
  float4* dst = (float4*)(h + (size_t)row * kD);
  for (int i = threadIdx.x; i < kD / 4; i += blockDim.x) dst[i] = src[i];
}

// ---------------- rmsnorm ----------------
__global__ __launch_bounds__(256) void k_rmsnorm(const float* __restrict__ x,
                                                 const float* __restrict__ w,
                                                 float* __restrict__ y) {
  int row = blockIdx.x;
  const float* xr = x + (size_t)row * kD;
  float ss = 0.f;
  for (int i = threadIdx.x; i < kD; i += 256) { float v = xr[i]; ss += v * v; }
  #pragma unroll
  for (int o = 1; o < 64; o <<= 1) ss += __shfl_xor(ss, o);
  __shared__ float wsum[4];
  int lane = threadIdx.x & 63, wid = threadIdx.x >> 6;
  if (lane == 0) wsum[wid] = ss;
  __syncthreads();
  float tot = wsum[0] + wsum[1] + wsum[2] + wsum[3];
  float inv = rsqrtf(tot / (float)kD + kEps);
  for (int i = threadIdx.x; i < kD; i += 256)
    y[(size_t)row * kD + i] = xr[i] * inv * w[i];
}

// ---------------- bf16 MFMA GEMM: C[M,N] (+)= A[M,K] @ B[K,N], fp32 in/out ----------------
template<int MODE>  // 0: C=A@B   1: C+=A@B
__global__ __launch_bounds__(256) void k_gemm_bf16(const float* __restrict__ A,
                                                   const float* __restrict__ Bsrc,
                                                   float* __restrict__ C,
                                                   int M, int N, int K) {
  __shared__ short As[128 * kPad];
  __shared__ short Bs[128 * kPad];
  int row0 = blockIdx.y * 128, col0 = blockIdx.x * 128;
  int tid = threadIdx.x;
  int wave = tid >> 6, lane = tid & 63;
  int wm = wave >> 1, wn = wave & 1;
  int l15 = lane & 15, l16 = lane >> 4;
  f32x4 acc[4][4];
  #pragma unroll
  for (int i = 0; i < 4; i++)
    #pragma unroll
    for (int j = 0; j < 4; j++) acc[i][j] = (f32x4){0.f, 0.f, 0.f, 0.f};

  int arow = tid >> 1, ahalf = tid & 1;
  int bkp = tid >> 4, bf4 = tid & 15;

  for (int k0 = 0; k0 < K; k0 += 32) {
    {
      const float* ag = A + (size_t)(row0 + arow) * K + k0 + ahalf * 16;
      float4 a0 = *(const float4*)(ag + 0), a1 = *(const float4*)(ag + 4);
      float4 a2 = *(const float4*)(ag + 8), a3 = *(const float4*)(ag + 12);
      uint4 u0 = { pk2(a0.x, a0.y), pk2(a0.z, a0.w), pk2(a1.x, a1.y), pk2(a1.z, a1.w) };
      uint4 u1 = { pk2(a2.x, a2.y), pk2(a2.z, a2.w), pk2(a3.x, a3.y), pk2(a3.z, a3.w) };
      *(uint4*)&As[arow * kPad + ahalf * 16] = u0;
      *(uint4*)&As[arow * kPad + ahalf * 16 + 8] = u1;
    }
    #pragma unroll
    for (int t = 0; t < 2; t++) {
      int colq = bf4 + 16 * t;
      const float* bg = Bsrc + (size_t)(k0 + 2 * bkp) * N + col0 + colq * 4;
      float4 lo = *(const float4*)bg;
      float4 hi = *(const float4*)(bg + N);
      *(uint32_t*)&Bs[(colq * 4 + 0) * kPad + 2 * bkp] = pk2(lo.x, hi.x);
      *(uint32_t*)&Bs[(colq * 4 + 1) * kPad + 2 * bkp] = pk2(lo.y, hi.y);
      *(uint32_t*)&Bs[(colq * 4 + 2) * kPad + 2 * bkp] = pk2(lo.z, hi.z);
      *(uint32_t*)&Bs[(colq * 4 + 3) * kPad + 2 * bkp] = pk2(lo.w, hi.w);
    }
    __syncthreads();
    bf16x8 af[4], bfr[4];
    #pragma unroll
    for (int mf = 0; mf < 4; mf++)
      af[mf] = *(const bf16x8*)&As[(wm * 64 + mf * 16 + l15) * kPad + l16 * 8];
    #pragma unroll
    for (int nf = 0; nf < 4; nf++)
      bfr[nf] = *(const bf16x8*)&Bs[(wn * 64 + nf * 16 + l15) * kPad + l16 * 8];
    #pragma unroll
    for (int mf = 0; mf < 4; mf++)
      #pragma unroll
      for (int nf = 0; nf < 4; nf++)
        acc[mf][nf] = __builtin_amdgcn_mfma_f32_16x16x32_bf16(af[mf], bfr[nf], acc[mf][nf], 0, 0, 0);
    __syncthreads();
  }
  #pragma unroll
  for (int mf = 0; mf < 4; mf++)
    #pragma unroll
    for (int nf = 0; nf < 4; nf++)
      #pragma unroll
      for (int r = 0; r < 4; r++) {
        int row = row0 + wm * 64 + mf * 16 + l16 * 4 + r;
        int col = col0 + wn * 64 + nf * 16 + l15;
        size_t off = (size_t)row * N + col;
        if (MODE == 1) C[off] += acc[mf][nf][r]; else C[off] = acc[mf][nf][r];
      }
}

// ---------------- FFN dual GEMM via MFMA: act = silu(A@W1) * (A@W3) ----------------
__global__ __launch_bounds__(256) void k_ffn13_bf16(const float* __restrict__ A,
                                                    const float* __restrict__ W1,
                                                    const float* __restrict__ W3,
                                                    float* __restrict__ act,
                                                    int M, int N, int K) {
  __shared__ short As[128 * kPad];
  __shared__ short B1[128 * kPad];
  __shared__ short B2[128 * kPad];
  int row0 = blockIdx.y * 128, col0 = blockIdx.x * 128;
  int tid = threadIdx.x;
  int wave = tid >> 6, lane = tid & 63;
  int wm = wave >> 1, wn = wave & 1;
  int l15 = lane & 15, l16 = lane >> 4;
  f32x4 acc1[4][4], acc2[4][4];
  #pragma unroll
  for (int i = 0; i < 4; i++)
    #pragma unroll
    for (int j = 0; j < 4; j++) {
      acc1[i][j] = (f32x4){0.f, 0.f, 0.f, 0.f};
      acc2[i][j] = (f32x4){0.f, 0.f, 0.f, 0.f};
    }
  int arow = tid >> 1, ahalf = tid & 1;
  int bkp = tid >> 4, bf4 = tid & 15;

  for (int k0 = 0; k0 < K; k0 += 32) {
    {
      const float* ag = A + (size_t)(row0 + arow) * K + k0 + ahalf * 16;
      float4 a0 = *(const float4*)(ag + 0), a1 = *(const float4*)(ag + 4);
      float4 a2 = *(const float4*)(ag + 8), a3 = *(const float4*)(ag + 12);
      uint4 u0 = { pk2(a0.x, a0.y), pk2(a0.z, a0.w), pk2(a1.x, a1.y), pk2(a1.z, a1.w) };
      uint4 u1 = { pk2(a2.x, a2.y), pk2(a2.z, a2.w), pk2(a3.x, a3.y), pk2(a3.z, a3.w) };
      *(uint4*)&As[arow * kPad + ahalf * 16] = u0;
      *(uint4*)&As[arow * kPad + ahalf * 16 + 8] = u1;
    }
    #pragma unroll
    for (int t = 0; t < 2; t++) {
      int colq = bf4 + 16 * t;
      const float* bg1 = W1 + (size_t)(k0 + 2 * bkp) * N + col0 + colq * 4;
      float4 lo = *(const float4*)bg1;
      float4 hi = *(const float4*)(bg1 + N);
      *(uint32_t*)&B1[(colq * 4 + 0) * kPad + 2 * bkp] = pk2(lo.x, hi.x);
      *(uint32_t*)&B1[(colq * 4 + 1) * kPad + 2 * bkp] = pk2(lo.y, hi.y);
      *(uint32_t*)&B1[(colq * 4 + 2) * kPad + 2 * bkp] = pk2(lo.z, hi.z);
      *(uint32_t*)&B1[(colq * 4 + 3) * kPad + 2 * bkp] = pk2(lo.w, hi.w);
      const float* bg3 = W3 + (size_t)(k0 + 2 * bkp) * N + col0 + colq * 4;
      float4 lo3 = *(const float4*)bg3;
      float4 hi3 = *(const float4*)(bg3 + N);
      *(uint32_t*)&B2[(colq * 4 + 0) * kPad + 2 * bkp] = pk2(lo3.x, hi3.x);
      *(uint32_t*)&B2[(colq * 4 + 1) * kPad + 2 * bkp] = pk2(lo3.y, hi3.y);
      *(uint32_t*)&B2[(colq * 4 + 2) * kPad + 2 * bkp] = pk2(lo3.z, hi3.z);
      *(uint32_t*)&B2[(colq * 4 + 3) * kPad + 2 * bkp] = pk2(lo3.w, hi3.w);
    }
    __syncthreads();
    bf16x8 af[4], b1f[4], b2f[4];
    #pragma unroll
    for (int mf = 0; mf < 4; mf++)
      af[mf] = *(const bf16x8*)&As[(wm * 64 + mf * 16 + l15) * kPad + l16 * 8];
    #pragma unroll
    for (int nf = 0; nf < 4; nf++) {
      b1f[nf] = *(const bf16x8*)&B1[(wn * 64 + nf * 16 + l15) * kPad + l16 * 8];
      b2f[nf] = *(const bf16x8*)&B2[(wn * 64 + nf * 16 + l15) * kPad + l16 * 8];
    }
    #pragma unroll
    for (int mf = 0; mf < 4; mf++)
      #pragma unroll
      for (int nf = 0; nf < 4; nf++) {
        acc1[mf][nf] = __builtin_amdgcn_mfma_f32_16x16x32_bf16(af[mf], b1f[nf], acc1[mf][nf], 0, 0, 0);
        acc2[mf][nf] = __builtin_amdgcn_mfma_f32_16x16x32_bf16(af[mf], b2f[nf], acc2[mf][nf], 0, 0, 0);
      }
    __syncthreads();
  }
  #pragma unroll
  for (int mf = 0; mf < 4; mf++)
    #pragma unroll
    for (int nf = 0; nf < 4; nf++)
      #pragma unroll
      for (int r = 0; r < 4; r++) {
        int row = row0 + wm * 64 + mf * 16 + l16 * 4 + r;
        int col = col0 + wn * 64 + nf * 16 + l15;
        float aa = acc1[mf][nf][r];
        float sg = 1.f / (1.f + expf(-aa));
        act[(size_t)row * N + col] = aa * sg * acc2[mf][nf][r];
      }
}

// ---------------- RoPE ----------------
__global__ void k_rope(float* __restrict__ q, float* __restrict__ k) {
  int idx = blockIdx.x * blockDim.x + threadIdx.x;
  if (idx >= kNS * kNH * kHALF) return;
  int d = idx & (kHALF - 1);
  int t = idx >> 5;
  int hh = t & (kNH - 1);
  int row = t >> 3;
  int s = row & (kS - 1);
  float freq = expf(-logf(10000.f) * ((float)d / (float)kHALF));
  float ang = (float)s * freq;
  float c = cosf(ang), sn = sinf(ang);
  size_t base = (size_t)row * kD + hh * kHD + d;
  float x1 = q[base], x2 = q[base + kHALF];
  q[base]         = x1 * c - x2 * sn;
  q[base + kHALF] = x1 * sn + x2 * c;
  x1 = k[base]; x2 = k[base + kHALF];
  k[base]         = x1 * c - x2 * sn;
  k[base + kHALF] = x1 * sn + x2 * c;
}

// ---------------- MFMA flash attention ----------------
// block = 256 (4 waves), grid (qt 0..7, n*h 0..159). Wave w: q rows [qt*64+w*16, +16).
// Swapped QK^T: S^T = mfma(A=K, B=Q) -> lane's col = its q row -> softmax lane-local.
// PV: O^T = mfma(A=V^T, B=P). All frags use verified layouts (row/col=lane&15, k=(lane>>4)*8+j).
__global__ __launch_bounds__(256) void k_attn_mfma(const float* __restrict__ q,
                                                   const float* __restrict__ k,
                                                   const float* __restrict__ v,
                                                   float* __restrict__ o) {
  int qt = blockIdx.x;
  int nh = blockIdx.y;
  int hh = nh & (kNH - 1), n = nh >> 3;
  int tid = threadIdx.x;
  int wq = tid >> 6, lane = tid & 63;
  int l15 = lane & 15, l16 = lane >> 4;
  __shared__ short Ks[64 * kStr];        // [kv][hd]
  __shared__ short Vt[64 * kStr];        // [hd][kv]  (V transposed)
  __shared__ short Ps[4][16 * kStr];     // per-wave P [q][kv]
  int q0 = qt * 64;
  int qrow = q0 + wq * 16 + l15;         // this lane's q row

  // Q B-frags (pre-scaled by 1/sqrt(HD)): Q[qrow][s*32 + l16*8 + j]
  bf16x8 qf[2];
  {
    const float* qg = q + (((size_t)(n * kS + qrow) * kNH + hh) << 6);
    #pragma unroll
    for (int s = 0; s < 2; s++) {
      float4 f0 = *(const float4*)(qg + s * 32 + l16 * 8);
      float4 f1 = *(const float4*)(qg + s * 32 + l16 * 8 + 4);
      union { bf16x8 v; uint4 u; } cv;
      cv.u.x = pk2(f0.x * 0.125f, f0.y * 0.125f);
      cv.u.y = pk2(f0.z * 0.125f, f0.w * 0.125f);
      cv.u.z = pk2(f1.x * 0.125f, f1.y * 0.125f);
      cv.u.w = pk2(f1.z * 0.125f, f1.w * 0.125f);
      qf[s] = cv.v;
    }
  }

  f32x4 oacc[4];                          // O^T frags: dt-tile -> rows d, col q=l15
  #pragma unroll
  for (int i = 0; i < 4; i++) oacc[i] = (f32x4){0.f, 0.f, 0.f, 0.f};
  float m_run = -1e30f, l_run = 0.f;

  int skv = tid & 63, sd0 = (tid >> 6) * 16;   // staging assignment

  for (int jt = 0; jt <= qt; jt++) {
    int j0 = jt * 64;
    __syncthreads();
    // ---- stage K [kv][hd] and V^T [hd][kv] ----
    {
      size_t gb = (((size_t)(n * kS + j0 + skv) * kNH + hh) << 6) + sd0;
      const float* kg = k + gb;
      float4 k0 = *(const float4*)(kg + 0), k1 = *(const float4*)(kg + 4);
      float4 k2 = *(const float4*)(kg + 8), k3 = *(const float4*)(kg + 12);
      uint4 u0 = { pk2(k0.x, k0.y), pk2(k0.z, k0.w), pk2(k1.x, k1.y), pk2(k1.z, k1.w) };
      uint4 u1 = { pk2(k2.x, k2.y), pk2(k2.z, k2.w), pk2(k3.x, k3.y), pk2(k3.z, k3.w) };
      *(uint4*)&Ks[skv * kStr + sd0] = u0;
      *(uint4*)&Ks[skv * kStr + sd0 + 8] = u1;
      const float* vg = v + gb;
      float vr[16];
      *(float4*)&vr[0]  = *(const float4*)(vg + 0);
      *(float4*)&vr[4]  = *(const float4*)(vg + 4);
      *(float4*)&vr[8]  = *(const float4*)(vg + 8);
      *(float4*)&vr[12] = *(const float4*)(vg + 12);
      #pragma unroll
      for (int i = 0; i < 16; i++) Vt[(sd0 + i) * kStr + skv] = bf1(vr[i]);
    }
    __syncthreads();

    // ---- S^T = K @ Q^T : 4 kt-tiles x K=64 ----
    f32x4 st[4];
    #pragma unroll
    for (int kt = 0; kt < 4; kt++) {
      bf16x8 ka0 = *(const bf16x8*)&Ks[(kt * 16 + l15) * kStr + l16 * 8];
      bf16x8 ka1 = *(const bf16x8*)&Ks[(kt * 16 + l15) * kStr + 32 + l16 * 8];
      f32x4 c = (f32x4){0.f, 0.f, 0.f, 0.f};
      c = __builtin_amdgcn_mfma_f32_16x16x32_bf16(ka0, qf[0], c, 0, 0, 0);
      c = __builtin_amdgcn_mfma_f32_16x16x32_bf16(ka1, qf[1], c, 0, 0, 0);
      st[kt] = c;
    }

    // ---- causal mask + lane-local online softmax (q = l15) ----
    float mx = m_run;
    #pragma unroll
    for (int kt = 0; kt < 4; kt++)
      #pragma unroll
      for (int r = 0; r < 4; r++) {
        int kvg = j0 + kt * 16 + l16 * 4 + r;
        if (kvg > qrow) st[kt][r] = -1e30f;
        mx = fmaxf(mx, st[kt][r]);
      }
    mx = fmaxf(mx, __shfl_xor(mx, 16));
    mx = fmaxf(mx, __shfl_xor(mx, 32));
    float sc = __expf(m_run - mx);
    float p[4][4];
    float rs = 0.f;
    #pragma unroll
    for (int kt = 0; kt < 4; kt++)
      #pragma unroll
      for (int r = 0; r < 4; r++) { p[kt][r] = __expf(st[kt][r] - mx); rs += p[kt][r]; }
    rs += __shfl_xor(rs, 16);
    rs += __shfl_xor(rs, 32);
    l_run = l_run * sc + rs;
    m_run = mx;
    #pragma unroll
    for (int dt = 0; dt < 4; dt++)
      #pragma unroll
      for (int r = 0; r < 4; r++) oacc[dt][r] *= sc;

    // ---- write P (bf16) to per-wave LDS [q][kv] ----
    #pragma unroll
    for (int kt = 0; kt < 4; kt++) {
      uint2 w2;
      w2.x = pk2(p[kt][0], p[kt][1]);
      w2.y = pk2(p[kt][2], p[kt][3]);
      *(uint2*)&Ps[wq][l15 * kStr + kt * 16 + l16 * 4] = w2;
    }
    asm volatile("s_waitcnt lgkmcnt(0)" ::: "memory");
    __builtin_amdgcn_sched_barrier(0);

    // ---- O^T += V^T @ P^T : 4 dt-tiles x K=64 (2 kv halves) ----
    bf16x8 pf0 = *(const bf16x8*)&Ps[wq][l15 * kStr + l16 * 8];
    bf16x8 pf1 = *(const bf16x8*)&Ps[wq][l15 * kStr + 32 + l16 * 8];
    #pragma unroll
    for (int dt = 0; dt < 4; dt++) {
      bf16x8 va0 = *(const bf16x8*)&Vt[(dt * 16 + l15) * kStr + l16 * 8];
      bf16x8 va1 = *(const bf16x8*)&Vt[(dt * 16 + l15) * kStr + 32 + l16 * 8];
      oacc[dt] = __builtin_amdgcn_mfma_f32_16x16x32_bf16(va0, pf0, oacc[dt], 0, 0, 0);
      oacc[dt] = __builtin_amdgcn_mfma_f32_16x16x32_bf16(va1, pf1, oacc[dt], 0, 0, 0);
    }
  }

  // ---- write O: lane has q=qrow, d = dt*16 + l16*4 + r ----
  float inv = 1.f / l_run;
  float* og = o + (((size_t)(n * kS + qrow) * kNH + hh) << 6);
  #pragma unroll
  for (int dt = 0; dt < 4; dt++) {
    float4 r;
    r.x = oacc[dt][0] * inv; r.y = oacc[dt][1] * inv;
    r.z = oacc[dt][2] * inv; r.w = oacc[dt][3] * inv;
    *(float4*)(og + dt * 16 + l16 * 4) = r;
  }
}

// ---------------- gather the 80 scoring rows ----------------
__global__ void k_gather(const float* __restrict__ xn, float* __restrict__ hs) {
  int r = blockIdx.x;
  int n = r / kLBL, li = r - n * kLBL;
  size_t src = ((size_t)n * kS + (kT - 1 + li)) * kD;
  for (int i = threadIdx.x; i < kD; i += blockDim.x) hs[r * kD + i] = xn[src + i];
}

// ---------------- logits partials via MFMA: one pass over lm_head ----------------
__global__ __launch_bounds__(256) void k_logits_mfma(const float* __restrict__ hs,
                                                     const float* __restrict__ lm,
                                                     float* __restrict__ part) {
  __shared__ short As[80 * kPad];
  __shared__ short Bs[256 * kPad];
  int tid = threadIdx.x;
  int wave = tid >> 6, lane = tid & 63;
  int l15 = lane & 15, l16 = lane >> 4;
  int col0 = blockIdx.x * 256;
  f32x4 acc[5][4];
  #pragma unroll
  for (int i = 0; i < 5; i++)
    #pragma unroll
    for (int j = 0; j < 4; j++) acc[i][j] = (f32x4){0.f, 0.f, 0.f, 0.f};

  int arow = tid >> 1, ahalf = tid & 1;
  int bkp = tid >> 4, bf4 = tid & 15;

  for (int k0 = 0; k0 < kD; k0 += 32) {
    if (tid < 160) {
      const float* ag = hs + (size_t)arow * kD + k0 + ahalf * 16;
      float4 a0 = *(const float4*)(ag + 0), a1 = *(const float4*)(ag + 4);
      float4 a2 = *(const float4*)(ag + 8), a3 = *(const float4*)(ag + 12);
      uint4 u0 = { pk2(a0.x, a0.y), pk2(a0.z, a0.w), pk2(a1.x, a1.y), pk2(a1.z, a1.w) };
      uint4 u1 = { pk2(a2.x, a2.y), pk2(a2.z, a2.w), pk2(a3.x, a3.y), pk2(a3.z, a3.w) };
      *(uint4*)&As[arow * kPad + ahalf * 16] = u0;
      *(uint4*)&As[arow * kPad + ahalf * 16 + 8] = u1;
    }
    #pragma unroll
    for (int t = 0; t < 4; t++) {
      int colq = bf4 + 16 * t;
      const float* bg = lm + (size_t)(k0 + 2 * bkp) * kV + col0 + colq * 4;
      float4 lo = *(const float4*)bg;
      float4 hi = *(const float4*)(bg + kV);
      *(uint32_t*)&Bs[(colq * 4 + 0) * kPad + 2 * bkp] = pk2(lo.x, hi.x);
      *(uint32_t*)&Bs[(colq * 4 + 1) * kPad + 2 * bkp] = pk2(lo.y, hi.y);
      *(uint32_t*)&Bs[(colq * 4 + 2) * kPad + 2 * bkp] = pk2(lo.z, hi.z);
      *(uint32_t*)&Bs[(colq * 4 + 3) * kPad + 2 * bkp] = pk2(lo.w, hi.w);
    }
    __syncthreads();
    bf16x8 af[5], bfr[4];
    #pragma unroll
    for (int mf = 0; mf < 5; mf++)
      af[mf] = *(const bf16x8*)&As[(mf * 16 + l15) * kPad + l16 * 8];
    #pragma unroll
    for (int nf = 0; nf < 4; nf++)
      bfr[nf] = *(const bf16x8*)&Bs[(wave * 64 + nf * 16 + l15) * kPad + l16 * 8];
    #pragma unroll
    for (int mf = 0; mf < 5; mf++)
      #pragma unroll
      for (int nf = 0; nf < 4; nf++)
        acc[mf][nf] = __builtin_amdgcn_mfma_f32_16x16x32_bf16(af[mf], bfr[nf], acc[mf][nf], 0, 0, 0);
    __syncthreads();
  }

  int chunk = blockIdx.x * 4 + wave;
  #pragma unroll
  for (int mf = 0; mf < 5; mf++)
    #pragma unroll
    for (int r = 0; r < 4; r++) {
      float mx = fmaxf(fmaxf(acc[mf][0][r], acc[mf][1][r]),
                       fmaxf(acc[mf][2][r], acc[mf][3][r]));
      #pragma unroll
      for (int off = 1; off < 16; off <<= 1) mx = fmaxf(mx, __shfl_xor(mx, off));
      float se = expf(acc[mf][0][r] - mx) + expf(acc[mf][1][r] - mx) +
                 expf(acc[mf][2][r] - mx) + expf(acc[mf][3][r] - mx);
      #pragma unroll
      for (int off = 1; off < 16; off <<= 1) se += __shfl_xor(se, off);
      if (l15 == 0) {
        int row = mf * 16 + l16 * 4 + r;
        size_t pi = ((size_t)row * kNChunk + chunk) * 2;
        part[pi] = mx; part[pi + 1] = se;
      }
    }
}

// ---------------- label-token logits ----------------
__global__ __launch_bounds__(64) void k_label_logits(const float* __restrict__ hs,
                                                     const float* __restrict__ lm,
                                                     const int* __restrict__ label_ids,
                                                     float* __restrict__ lbl) {
  int r = blockIdx.x;
  int li = r & 3, n = r >> 2, lab = n / kB;
  int tok = label_ids[lab * kLBL + li];
  int lane = threadIdx.x;
  float dv = 0.f;
  for (int d2 = lane; d2 < kD; d2 += 64) dv += hs[r * kD + d2] * lm[(size_t)d2 * kV + tok];
  #pragma unroll
  for (int o2 = 1; o2 < 64; o2 <<= 1) dv += __shfl_xor(dv, o2);
  if (lane == 0) lbl[r] = dv;
}

// ---------------- final reduce ----------------
__global__ __launch_bounds__(64) void k_final(const float* __restrict__ part,
                                              const float* __restrict__ lbl,
                                              float* __restrict__ out) {
  int n = blockIdx.x;
  int lab = n / kB, b = n - lab * kB;
  int lane = threadIdx.x;
  float res = 0.f;
  for (int li = 0; li < kLBL; li++) {
    int r = n * kLBL + li;
    const float* pr = part + (size_t)r * kNChunk * 2;
    float mx = -1e30f;
    for (int c = lane; c < kNChunk; c += 64) mx = fmaxf(mx, pr[c * 2]);
    #pragma unroll
    for (int o2 = 1; o2 < 64; o2 <<= 1) mx = fmaxf(mx, __shfl_xor(mx, o2));
    float sum = 0.f;
    for (int c = lane; c < kNChunk; c += 64) sum += pr[c * 2 + 1] * expf(pr[c * 2] - mx);
    #pragma unroll
    for (int o2 = 1; o2 < 64; o2 <<= 1) sum += __shfl_xor(sum, o2);
    res += lbl[r] - (mx + logf(sum));
  }
  if (lane == 0) out[b * kNLAB + lab] = res;
}

extern "C" void kernel_launch(void* const* d_in, const int* in_sizes, int n_in,
                              void* d_out, int out_size, void* d_ws, size_t ws_size,
                              hipStream_t stream) {
  const int*   input_ids    = (const int*)d_in[0];
  const int*   label_ids    = (const int*)d_in[1];
  const float* emb          = (const float*)d_in[2];
  const float* wq           = (const float*)d_in[3];
  const float* wk           = (const float*)d_in[4];
  const float* wv           = (const float*)d_in[5];
  const float* wo           = (const float*)d_in[6];
  const float* w1           = (const float*)d_in[7];
  const float* w2           = (const float*)d_in[8];
  const float* w3           = (const float*)d_in[9];
  const float* attn_norm_w  = (const float*)d_in[10];
  const float* ffn_norm_w   = (const float*)d_in[11];
  const float* final_norm_w = (const float*)d_in[12];
  const float* lm_head      = (const float*)d_in[13];
  float* out = (float*)d_out;

  char* ws = (char*)d_ws;
  float* h    = (float*)(ws);                 // 20,971,520 B
  float* xn   = (float*)(ws + 20971520);      // 20,971,520
  float* q    = (float*)(ws + 41943040);      // 20,971,520
  float* kk   = (float*)(ws + 62914560);      // 20,971,520
  float* vv   = (float*)(ws + 83886080);      // 20,971,520
  float* big  = (float*)(ws + 104857600);     // 57,671,680 (attn-out / ffn act)
  float* hs   = (float*)(ws + 162529280);     // 163,840
  float* part = (float*)(ws + 162693120);     // 1,280,000
  float* lbl  = (float*)(ws + 163973120);     // 320

  k_embed<<<kNS, 128, 0, stream>>>(input_ids, label_ids, emb, h);

  for (int l = 0; l < kNL; l++) {
    k_rmsnorm<<<kNS, 256, 0, stream>>>(h, attn_norm_w + (size_t)l * kD, xn);
    dim3 gqkv(kD / 128, kNS / 128);
    k_gemm_bf16<0><<<gqkv, 256, 0, stream>>>(xn, wq + (size_t)l * kD * kD, q,  kNS, kD, kD);
    k_gemm_bf16<0><<<gqkv, 256, 0, stream>>>(xn, wk + (size_t)l * kD * kD, kk, kNS, kD, kD);
    k_gemm_bf16<0><<<gqkv, 256, 0, stream>>>(xn, wv + (size_t)l * kD * kD, vv, kNS, kD, kD);
    k_rope<<<(kNS * kNH * kHALF) / 256, 256, 0, stream>>>(q, kk);
    dim3 gattn(kS / 64, kNSeq * kNH);
    k_attn_mfma<<<gattn, 256, 0, stream>>>(q, kk, vv, big);
    k_gemm_bf16<1><<<gqkv, 256, 0, stream>>>(big, wo + (size_t)l * kD * kD, h, kNS, kD, kD);
    k_rmsnorm<<<kNS, 256, 0, stream>>>(h, ffn_norm_w + (size_t)l * kD, xn);
    dim3 gffn(kHID / 128, kNS / 128);
    k_ffn13_bf16<<<gffn, 256, 0, stream>>>(xn, w1 + (size_t)l * kD * kHID,
                                           w3 + (size_t)l * kD * kHID, big, kNS, kHID, kD);
    dim3 gw2(kD / 128, kNS / 128);
    k_gemm_bf16<1><<<gw2, 256, 0, stream>>>(big, w2 + (size_t)l * kHID * kD, h, kNS, kD, kHID);
  }

  k_rmsnorm<<<kNS, 256, 0, stream>>>(h, final_norm_w, xn);
  k_gather<<<kNSeq * kLBL, 128, 0, stream>>>(xn, hs);
  k_logits_mfma<<<kV / 256, 256, 0, stream>>>(hs, lm_head, part);
  k_label_logits<<<kNSeq * kLBL, 64, 0, stream>>>(hs, lm_head, label_ids, lbl);
  k_final<<<kNSeq, 64, 0, stream>>>(part, lbl, out);
}

// Round 5
// 753.360 us; speedup vs baseline: 5.8147x; 1.4113x over previous
//
#include <hip/hip_runtime.h>
#include <math.h>

typedef unsigned short u16;
typedef unsigned int u32;

namespace {
constexpr int kV = 128000, kD = 512, kNH = 8, kNL = 2, kHID = 1408;
constexpr int kHD = 64, kB = 4, kT = 508, kNLAB = 5, kLBL = 4;
constexpr int kS = 512;                 // T + LBL
constexpr int kNSeq = kNLAB * kB;       // 20
constexpr int kNS = kNSeq * kS;         // 10240 rows
constexpr float kEps = 1e-5f;
constexpr int kNChunk = 2000;           // 64-col partial chunks
constexpr int kPad = 56;                // GEMM LDS row stride (bf16)
constexpr int kStr = 72;                // attn LDS row stride (bf16)
constexpr int kPL = 3211264;            // per-layer transposed-weight elems
// wT element offsets within a layer
constexpr int oWQ = 0, oWK = 262144, oWV = 524288, oWO = 786432;
constexpr int oW1 = 1048576, oW3 = 1769472, oW2 = 2490368;
}

typedef __attribute__((ext_vector_type(8))) short bf16x8;
typedef __attribute__((ext_vector_type(4))) float f32x4;

__device__ inline u32 pk2(float lo, float hi) {   // RNE fp32->bf16 pair
  u32 ul = __builtin_bit_cast(u32, lo);
  u32 uh = __builtin_bit_cast(u32, hi);
  ul += 0x7fffu + ((ul >> 16) & 1u);
  uh += 0x7fffu + ((uh >> 16) & 1u);
  return (ul >> 16) | (uh & 0xffff0000u);
}
__device__ inline u16 bf1(float x) {
  u32 u = __builtin_bit_cast(u32, x);
  u += 0x7fffu + ((u >> 16) & 1u);
  return (u16)(u >> 16);
}
__device__ inline float bf2f(u16 u) {
  return __builtin_bit_cast(float, ((u32)u) << 16);
}

// ---------------- weight transpose+convert: dst[n][k] = src[k][n]*scale ----------------
__global__ __launch_bounds__(256) void k_wtrans(const float* __restrict__ src,
                                                u16* __restrict__ dst,
                                                int K, int N, float scale) {
  __shared__ float t[32][33];
  int bn = blockIdx.x * 32, bk = blockIdx.y * 32;
  int tid = threadIdx.x;
  int r = tid >> 3, c4 = (tid & 7) * 4;
  float4 v = *(const float4*)(src + (size_t)(bk + r) * N + bn + c4);
  t[r][c4 + 0] = v.x * scale; t[r][c4 + 1] = v.y * scale;
  t[r][c4 + 2] = v.z * scale; t[r][c4 + 3] = v.w * scale;
  __syncthreads();
  uint2 o;
  o.x = pk2(t[c4 + 0][r], t[c4 + 1][r]);
  o.y = pk2(t[c4 + 2][r], t[c4 + 3][r]);
  *(uint2*)&dst[(size_t)(bn + r) * K + bk + c4] = o;
}

// ---------------- embedding (fp32 h) ----------------
__global__ void k_embed(const int* __restrict__ input_ids, const int* __restrict__ label_ids,
                        const float* __restrict__ emb, float* __restrict__ h) {
  int row = blockIdx.x;
  int n = row / kS, s = row - n * kS;
  int lab = n / kB, b = n - lab * kB;
  int tok = (s < kT) ? input_ids[b * kT + s] : label_ids[lab * kLBL + (s - kT)];
  const float4* src = (const float4*)(emb + (size_t)tok * kD);
  float4* dst = (float4*)(h + (size_t)row * kD);
  for (int i = threadIdx.x; i < kD / 4; i += blockDim.x) dst[i] = src[i];
}

// ---------------- rmsnorm: fp32 in, bf16 out ----------------
__global__ __launch_bounds__(256) void k_rmsnorm(const float* __restrict__ x,
                                                 const float* __restrict__ w,
                                                 u16* __restrict__ y) {
  int row = blockIdx.x;
  int tid = threadIdx.x;
  const float* xr = x + (size_t)row * kD;
  int i = tid * 2;
  float v0 = xr[i], v1 = xr[i + 1];
  float ss = v0 * v0 + v1 * v1;
  #pragma unroll
  for (int o = 1; o < 64; o <<= 1) ss += __shfl_xor(ss, o);
  __shared__ float wsum[4];
  int lane = tid & 63, wid = tid >> 6;
  if (lane == 0) wsum[wid] = ss;
  __syncthreads();
  float tot = wsum[0] + wsum[1] + wsum[2] + wsum[3];
  float inv = rsqrtf(tot / (float)kD + kEps);
  *(u32*)&y[(size_t)row * kD + i] = pk2(v0 * inv * w[i], v1 * inv * w[i + 1]);
}

// ---------------- bf16 MFMA GEMM: A[M,K]bf16 @ Bt[N,K]bf16 ----------------
// MODE 0: C bf16 = A@B    MODE 1: C fp32 += A@B
// 1D grid (XCD-chunk swizzled), 128x128 tile, 4 waves, K-step 32.
template<int MODE>
__global__ __launch_bounds__(256) void k_gemm_bf16(const u16* __restrict__ A,
                                                   const u16* __restrict__ Bt,
                                                   void* __restrict__ Cv,
                                                   int M, int N, int K, int gx) {
  __shared__ u16 As[128 * kPad];
  __shared__ u16 Bs[128 * kPad];
  int nwg = gridDim.x;
  int q8 = nwg >> 3;
  int wg = (blockIdx.x & 7) * q8 + (blockIdx.x >> 3);
  int by = wg / gx, bx = wg - by * gx;
  int row0 = by * 128, col0 = bx * 128;
  int tid = threadIdx.x;
  int wave = tid >> 6, lane = tid & 63;
  int wm = wave >> 1, wn = wave & 1;
  int l15 = lane & 15, l16 = lane >> 4;
  f32x4 acc[4][4];
  #pragma unroll
  for (int i = 0; i < 4; i++)
    #pragma unroll
    for (int j = 0; j < 4; j++) acc[i][j] = (f32x4){0.f, 0.f, 0.f, 0.f};

  int srow = tid >> 1, shalf = tid & 1;

  for (int k0 = 0; k0 < K; k0 += 32) {
    const u16* ag = A + (size_t)(row0 + srow) * K + k0 + shalf * 16;
    *(uint4*)&As[srow * kPad + shalf * 16]     = *(const uint4*)ag;
    *(uint4*)&As[srow * kPad + shalf * 16 + 8] = *(const uint4*)(ag + 8);
    const u16* bg = Bt + (size_t)(col0 + srow) * K + k0 + shalf * 16;
    *(uint4*)&Bs[srow * kPad + shalf * 16]     = *(const uint4*)bg;
    *(uint4*)&Bs[srow * kPad + shalf * 16 + 8] = *(const uint4*)(bg + 8);
    __syncthreads();
    bf16x8 af[4], bfr[4];
    #pragma unroll
    for (int mf = 0; mf < 4; mf++)
      af[mf] = *(const bf16x8*)&As[(wm * 64 + mf * 16 + l15) * kPad + l16 * 8];
    #pragma unroll
    for (int nf = 0; nf < 4; nf++)
      bfr[nf] = *(const bf16x8*)&Bs[(wn * 64 + nf * 16 + l15) * kPad + l16 * 8];
    #pragma unroll
    for (int mf = 0; mf < 4; mf++)
      #pragma unroll
      for (int nf = 0; nf < 4; nf++)
        acc[mf][nf] = __builtin_amdgcn_mfma_f32_16x16x32_bf16(af[mf], bfr[nf], acc[mf][nf], 0, 0, 0);
    __syncthreads();
  }
  #pragma unroll
  for (int mf = 0; mf < 4; mf++)
    #pragma unroll
    for (int nf = 0; nf < 4; nf++)
      #pragma unroll
      for (int r = 0; r < 4; r++) {
        int row = row0 + wm * 64 + mf * 16 + l16 * 4 + r;
        int col = col0 + wn * 64 + nf * 16 + l15;
        size_t off = (size_t)row * N + col;
        if (MODE == 1) ((float*)Cv)[off] += acc[mf][nf][r];
        else           ((u16*)Cv)[off] = bf1(acc[mf][nf][r]);
      }
}

// ---------------- FFN dual GEMM: act bf16 = silu(A@W1) * (A@W3) ----------------
__global__ __launch_bounds__(256) void k_ffn13_bf16(const u16* __restrict__ A,
                                                    const u16* __restrict__ W1t,
                                                    const u16* __restrict__ W3t,
                                                    u16* __restrict__ act,
                                                    int M, int N, int K, int gx) {
  __shared__ u16 As[128 * kPad];
  __shared__ u16 B1[128 * kPad];
  __shared__ u16 B2[128 * kPad];
  int nwg = gridDim.x;
  int q8 = nwg >> 3;
  int wg = (blockIdx.x & 7) * q8 + (blockIdx.x >> 3);
  int by = wg / gx, bx = wg - by * gx;
  int row0 = by * 128, col0 = bx * 128;
  int tid = threadIdx.x;
  int wave = tid >> 6, lane = tid & 63;
  int wm = wave >> 1, wn = wave & 1;
  int l15 = lane & 15, l16 = lane >> 4;
  f32x4 acc1[4][4], acc2[4][4];
  #pragma unroll
  for (int i = 0; i < 4; i++)
    #pragma unroll
    for (int j = 0; j < 4; j++) {
      acc1[i][j] = (f32x4){0.f, 0.f, 0.f, 0.f};
      acc2[i][j] = (f32x4){0.f, 0.f, 0.f, 0.f};
    }
  int srow = tid >> 1, shalf = tid & 1;

  for (int k0 = 0; k0 < K; k0 += 32) {
    const u16* ag = A + (size_t)(row0 + srow) * K + k0 + shalf * 16;
    *(uint4*)&As[srow * kPad + shalf * 16]     = *(const uint4*)ag;
    *(uint4*)&As[srow * kPad + shalf * 16 + 8] = *(const uint4*)(ag + 8);
    const u16* b1g = W1t + (size_t)(col0 + srow) * K + k0 + shalf * 16;
    *(uint4*)&B1[srow * kPad + shalf * 16]     = *(const uint4*)b1g;
    *(uint4*)&B1[srow * kPad + shalf * 16 + 8] = *(const uint4*)(b1g + 8);
    const u16* b3g = W3t + (size_t)(col0 + srow) * K + k0 + shalf * 16;
    *(uint4*)&B2[srow * kPad + shalf * 16]     = *(const uint4*)b3g;
    *(uint4*)&B2[srow * kPad + shalf * 16 + 8] = *(const uint4*)(b3g + 8);
    __syncthreads();
    bf16x8 af[4], b1f[4], b2f[4];
    #pragma unroll
    for (int mf = 0; mf < 4; mf++)
      af[mf] = *(const bf16x8*)&As[(wm * 64 + mf * 16 + l15) * kPad + l16 * 8];
    #pragma unroll
    for (int nf = 0; nf < 4; nf++) {
      b1f[nf] = *(const bf16x8*)&B1[(wn * 64 + nf * 16 + l15) * kPad + l16 * 8];
      b2f[nf] = *(const bf16x8*)&B2[(wn * 64 + nf * 16 + l15) * kPad + l16 * 8];
    }
    #pragma unroll
    for (int mf = 0; mf < 4; mf++)
      #pragma unroll
      for (int nf = 0; nf < 4; nf++) {
        acc1[mf][nf] = __builtin_amdgcn_mfma_f32_16x16x32_bf16(af[mf], b1f[nf], acc1[mf][nf], 0, 0, 0);
        acc2[mf][nf] = __builtin_amdgcn_mfma_f32_16x16x32_bf16(af[mf], b2f[nf], acc2[mf][nf], 0, 0, 0);
      }
    __syncthreads();
  }
  #pragma unroll
  for (int mf = 0; mf < 4; mf++)
    #pragma unroll
    for (int nf = 0; nf < 4; nf++)
      #pragma unroll
      for (int r = 0; r < 4; r++) {
        int row = row0 + wm * 64 + mf * 16 + l16 * 4 + r;
        int col = col0 + wn * 64 + nf * 16 + l15;
        float aa = acc1[mf][nf][r];
        float sg = 1.f / (1.f + expf(-aa));
        act[(size_t)row * N + col] = bf1(aa * sg * acc2[mf][nf][r]);
      }
}

// ---------------- RoPE on bf16 q/k, 2 dims per thread ----------------
__global__ void k_rope(u16* __restrict__ q, u16* __restrict__ k) {
  int idx = blockIdx.x * blockDim.x + threadIdx.x;   // kNS*kNH*16
  if (idx >= kNS * kNH * 16) return;
  int d2 = (idx & 15) * 2;
  int t = idx >> 4;
  int hh = t & (kNH - 1);
  int row = t >> 3;
  int s = row & (kS - 1);
  float fa = expf(-0.2878231366242558f * (float)d2);        // 10000^(-d/32)
  float fb = expf(-0.2878231366242558f * (float)(d2 + 1));
  float aa = (float)s * fa, ab = (float)s * fb;
  float ca = cosf(aa), sa = sinf(aa);
  float cb = cosf(ab), sb = sinf(ab);
  size_t base = (size_t)row * kD + hh * kHD + d2;
  u32 q1 = *(u32*)&q[base], q2 = *(u32*)&q[base + 32];
  float x1a = bf2f((u16)q1), x1b = bf2f((u16)(q1 >> 16));
  float x2a = bf2f((u16)q2), x2b = bf2f((u16)(q2 >> 16));
  *(u32*)&q[base]      = pk2(x1a * ca - x2a * sa, x1b * cb - x2b * sb);
  *(u32*)&q[base + 32] = pk2(x1a * sa + x2a * ca, x1b * sb + x2b * cb);
  u32 k1 = *(u32*)&k[base], k2 = *(u32*)&k[base + 32];
  x1a = bf2f((u16)k1); x1b = bf2f((u16)(k1 >> 16));
  x2a = bf2f((u16)k2); x2b = bf2f((u16)(k2 >> 16));
  *(u32*)&k[base]      = pk2(x1a * ca - x2a * sa, x1b * cb - x2b * sb);
  *(u32*)&k[base + 32] = pk2(x1a * sa + x2a * ca, x1b * sb + x2b * cb);
}

// ---------------- MFMA flash attention (bf16 I/O, q pre-scaled via wqT) ----------------
__global__ __launch_bounds__(256) void k_attn_mfma(const u16* __restrict__ q,
                                                   const u16* __restrict__ k,
                                                   const u16* __restrict__ v,
                                                   u16* __restrict__ o) {
  int qt = blockIdx.x;
  int nh = blockIdx.y;
  int hh = nh & (kNH - 1), n = nh >> 3;
  int tid = threadIdx.x;
  int wq = tid >> 6, lane = tid & 63;
  int l15 = lane & 15, l16 = lane >> 4;
  __shared__ u16 Ks[64 * kStr];        // [kv][hd]
  __shared__ u16 Vt[64 * kStr];        // [hd][kv]
  __shared__ u16 Ps[4][16 * kStr];     // per-wave P [q][kv]
  int q0 = qt * 64;
  int qrow = q0 + wq * 16 + l15;

  bf16x8 qf[2];
  {
    const u16* qg = q + (size_t)(n * kS + qrow) * kD + hh * kHD;
    qf[0] = *(const bf16x8*)(qg + l16 * 8);
    qf[1] = *(const bf16x8*)(qg + 32 + l16 * 8);
  }

  f32x4 oacc[4];
  #pragma unroll
  for (int i = 0; i < 4; i++) oacc[i] = (f32x4){0.f, 0.f, 0.f, 0.f};
  float m_run = -1e30f, l_run = 0.f;

  int skv = tid & 63, sd0 = (tid >> 6) * 16;

  for (int jt = 0; jt <= qt; jt++) {
    int j0 = jt * 64;
    __syncthreads();
    {
      size_t gb = (size_t)(n * kS + j0 + skv) * kD + hh * kHD + sd0;
      const u16* kg = k + gb;
      *(uint4*)&Ks[skv * kStr + sd0]     = *(const uint4*)kg;
      *(uint4*)&Ks[skv * kStr + sd0 + 8] = *(const uint4*)(kg + 8);
      union { uint4 u4[2]; u16 us[16]; } vb;
      vb.u4[0] = *(const uint4*)(v + gb);
      vb.u4[1] = *(const uint4*)(v + gb + 8);
      #pragma unroll
      for (int i = 0; i < 16; i++) Vt[(sd0 + i) * kStr + skv] = vb.us[i];
    }
    __syncthreads();

    f32x4 st[4];
    #pragma unroll
    for (int kt = 0; kt < 4; kt++) {
      bf16x8 ka0 = *(const bf16x8*)&Ks[(kt * 16 + l15) * kStr + l16 * 8];
      bf16x8 ka1 = *(const bf16x8*)&Ks[(kt * 16 + l15) * kStr + 32 + l16 * 8];
      f32x4 c = (f32x4){0.f, 0.f, 0.f, 0.f};
      c = __builtin_amdgcn_mfma_f32_16x16x32_bf16(ka0, qf[0], c, 0, 0, 0);
      c = __builtin_amdgcn_mfma_f32_16x16x32_bf16(ka1, qf[1], c, 0, 0, 0);
      st[kt] = c;
    }

    float mx = m_run;
    #pragma unroll
    for (int kt = 0; kt < 4; kt++)
      #pragma unroll
      for (int r = 0; r < 4; r++) {
        int kvg = j0 + kt * 16 + l16 * 4 + r;
        if (kvg > qrow) st[kt][r] = -1e30f;
        mx = fmaxf(mx, st[kt][r]);
      }
    mx = fmaxf(mx, __shfl_xor(mx, 16));
    mx = fmaxf(mx, __shfl_xor(mx, 32));
    float sc = __expf(m_run - mx);
    float p[4][4];
    float rs = 0.f;
    #pragma unroll
    for (int kt = 0; kt < 4; kt++)
      #pragma unroll
      for (int r = 0; r < 4; r++) { p[kt][r] = __expf(st[kt][r] - mx); rs += p[kt][r]; }
    rs += __shfl_xor(rs, 16);
    rs += __shfl_xor(rs, 32);
    l_run = l_run * sc + rs;
    m_run = mx;
    #pragma unroll
    for (int dt = 0; dt < 4; dt++)
      #pragma unroll
      for (int r = 0; r < 4; r++) oacc[dt][r] *= sc;

    #pragma unroll
    for (int kt = 0; kt < 4; kt++) {
      uint2 w2;
      w2.x = pk2(p[kt][0], p[kt][1]);
      w2.y = pk2(p[kt][2], p[kt][3]);
      *(uint2*)&Ps[wq][l15 * kStr + kt * 16 + l16 * 4] = w2;
    }
    asm volatile("s_waitcnt lgkmcnt(0)" ::: "memory");
    __builtin_amdgcn_sched_barrier(0);

    bf16x8 pf0 = *(const bf16x8*)&Ps[wq][l15 * kStr + l16 * 8];
    bf16x8 pf1 = *(const bf16x8*)&Ps[wq][l15 * kStr + 32 + l16 * 8];
    #pragma unroll
    for (int dt = 0; dt < 4; dt++) {
      bf16x8 va0 = *(const bf16x8*)&Vt[(dt * 16 + l15) * kStr + l16 * 8];
      bf16x8 va1 = *(const bf16x8*)&Vt[(dt * 16 + l15) * kStr + 32 + l16 * 8];
      oacc[dt] = __builtin_amdgcn_mfma_f32_16x16x32_bf16(va0, pf0, oacc[dt], 0, 0, 0);
      oacc[dt] = __builtin_amdgcn_mfma_f32_16x16x32_bf16(va1, pf1, oacc[dt], 0, 0, 0);
    }
  }

  float inv = 1.f / l_run;
  u16* og = o + (size_t)(n * kS + qrow) * kD + hh * kHD;
  #pragma unroll
  for (int dt = 0; dt < 4; dt++) {
    uint2 ow;
    ow.x = pk2(oacc[dt][0] * inv, oacc[dt][1] * inv);
    ow.y = pk2(oacc[dt][2] * inv, oacc[dt][3] * inv);
    *(uint2*)(og + dt * 16 + l16 * 4) = ow;
  }
}

// ---------------- gather the 80 scoring rows (bf16) ----------------
__global__ void k_gather(const u16* __restrict__ xn, u16* __restrict__ hs) {
  int r = blockIdx.x;
  int n = r / kLBL, li = r - n * kLBL;
  size_t src = ((size_t)n * kS + (kT - 1 + li)) * kD;
  int i = threadIdx.x;                  // 128 threads, 4 elems each
  *(uint2*)&hs[(size_t)r * kD + i * 4] = *(const uint2*)&xn[src + i * 4];
}

// ---------------- logits partials via MFMA (A bf16, lm fp32 streamed) ----------------
__global__ __launch_bounds__(256) void k_logits_mfma(const u16* __restrict__ hs,
                                                     const float* __restrict__ lm,
                                                     float* __restrict__ part) {
  __shared__ u16 As[80 * kPad];
  __shared__ u16 Bs[256 * kPad];
  int tid = threadIdx.x;
  int wave = tid >> 6, lane = tid & 63;
  int l15 = lane & 15, l16 = lane >> 4;
  int col0 = blockIdx.x * 256;
  f32x4 acc[5][4];
  #pragma unroll
  for (int i = 0; i < 5; i++)
    #pragma unroll
    for (int j = 0; j < 4; j++) acc[i][j] = (f32x4){0.f, 0.f, 0.f, 0.f};

  int arow = tid >> 1, ahalf = tid & 1;
  int bkp = tid >> 4, bf4 = tid & 15;

  for (int k0 = 0; k0 < kD; k0 += 32) {
    if (tid < 160) {
      const u16* ag = hs + (size_t)arow * kD + k0 + ahalf * 16;
      *(uint4*)&As[arow * kPad + ahalf * 16]     = *(const uint4*)ag;
      *(uint4*)&As[arow * kPad + ahalf * 16 + 8] = *(const uint4*)(ag + 8);
    }
    #pragma unroll
    for (int t = 0; t < 4; t++) {
      int colq = bf4 + 16 * t;
      const float* bg = lm + (size_t)(k0 + 2 * bkp) * kV + col0 + colq * 4;
      float4 lo = *(const float4*)bg;
      float4 hi = *(const float4*)(bg + kV);
      *(u32*)&Bs[(colq * 4 + 0) * kPad + 2 * bkp] = pk2(lo.x, hi.x);
      *(u32*)&Bs[(colq * 4 + 1) * kPad + 2 * bkp] = pk2(lo.y, hi.y);
      *(u32*)&Bs[(colq * 4 + 2) * kPad + 2 * bkp] = pk2(lo.z, hi.z);
      *(u32*)&Bs[(colq * 4 + 3) * kPad + 2 * bkp] = pk2(lo.w, hi.w);
    }
    __syncthreads();
    bf16x8 af[5], bfr[4];
    #pragma unroll
    for (int mf = 0; mf < 5; mf++)
      af[mf] = *(const bf16x8*)&As[(mf * 16 + l15) * kPad + l16 * 8];
    #pragma unroll
    for (int nf = 0; nf < 4; nf++)
      bfr[nf] = *(const bf16x8*)&Bs[(wave * 64 + nf * 16 + l15) * kPad + l16 * 8];
    #pragma unroll
    for (int mf = 0; mf < 5; mf++)
      #pragma unroll
      for (int nf = 0; nf < 4; nf++)
        acc[mf][nf] = __builtin_amdgcn_mfma_f32_16x16x32_bf16(af[mf], bfr[nf], acc[mf][nf], 0, 0, 0);
    __syncthreads();
  }

  int chunk = blockIdx.x * 4 + wave;
  #pragma unroll
  for (int mf = 0; mf < 5; mf++)
    #pragma unroll
    for (int r = 0; r < 4; r++) {
      float mx = fmaxf(fmaxf(acc[mf][0][r], acc[mf][1][r]),
                       fmaxf(acc[mf][2][r], acc[mf][3][r]));
      #pragma unroll
      for (int off = 1; off < 16; off <<= 1) mx = fmaxf(mx, __shfl_xor(mx, off));
      float se = expf(acc[mf][0][r] - mx) + expf(acc[mf][1][r] - mx) +
                 expf(acc[mf][2][r] - mx) + expf(acc[mf][3][r] - mx);
      #pragma unroll
      for (int off = 1; off < 16; off <<= 1) se += __shfl_xor(se, off);
      if (l15 == 0) {
        int row = mf * 16 + l16 * 4 + r;
        size_t pi = ((size_t)row * kNChunk + chunk) * 2;
        part[pi] = mx; part[pi + 1] = se;
      }
    }
}

// ---------------- label-token logits ----------------
__global__ __launch_bounds__(64) void k_label_logits(const u16* __restrict__ hs,
                                                     const float* __restrict__ lm,
                                                     const int* __restrict__ label_ids,
                                                     float* __restrict__ lbl) {
  int r = blockIdx.x;
  int li = r & 3, n = r >> 2, lab = n / kB;
  int tok = label_ids[lab * kLBL + li];
  int lane = threadIdx.x;
  float dv = 0.f;
  for (int d2 = lane; d2 < kD; d2 += 64)
    dv += bf2f(hs[(size_t)r * kD + d2]) * lm[(size_t)d2 * kV + tok];
  #pragma unroll
  for (int o2 = 1; o2 < 64; o2 <<= 1) dv += __shfl_xor(dv, o2);
  if (lane == 0) lbl[r] = dv;
}

// ---------------- final reduce ----------------
__global__ __launch_bounds__(64) void k_final(const float* __restrict__ part,
                                              const float* __restrict__ lbl,
                                              float* __restrict__ out) {
  int n = blockIdx.x;
  int lab = n / kB, b = n - lab * kB;
  int lane = threadIdx.x;
  float res = 0.f;
  for (int li = 0; li < kLBL; li++) {
    int r = n * kLBL + li;
    const float* pr = part + (size_t)r * kNChunk * 2;
    float mx = -1e30f;
    for (int c = lane; c < kNChunk; c += 64) mx = fmaxf(mx, pr[c * 2]);
    #pragma unroll
    for (int o2 = 1; o2 < 64; o2 <<= 1) mx = fmaxf(mx, __shfl_xor(mx, o2));
    float sum = 0.f;
    for (int c = lane; c < kNChunk; c += 64) sum += pr[c * 2 + 1] * expf(pr[c * 2] - mx);
    #pragma unroll
    for (int o2 = 1; o2 < 64; o2 <<= 1) sum += __shfl_xor(sum, o2);
    res += lbl[r] - (mx + logf(sum));
  }
  if (lane == 0) out[b * kNLAB + lab] = res;
}

extern "C" void kernel_launch(void* const* d_in, const int* in_sizes, int n_in,
                              void* d_out, int out_size, void* d_ws, size_t ws_size,
                              hipStream_t stream) {
  const int*   input_ids    = (const int*)d_in[0];
  const int*   label_ids    = (const int*)d_in[1];
  const float* emb          = (const float*)d_in[2];
  const float* wq           = (const float*)d_in[3];
  const float* wk           = (const float*)d_in[4];
  const float* wv           = (const float*)d_in[5];
  const float* wo           = (const float*)d_in[6];
  const float* w1           = (const float*)d_in[7];
  const float* w2           = (const float*)d_in[8];
  const float* w3           = (const float*)d_in[9];
  const float* attn_norm_w  = (const float*)d_in[10];
  const float* ffn_norm_w   = (const float*)d_in[11];
  const float* final_norm_w = (const float*)d_in[12];
  const float* lm_head      = (const float*)d_in[13];
  float* out = (float*)d_out;

  char* ws = (char*)d_ws;
  float* h    = (float*)(ws);                  // 20,971,520 B fp32
  u16*   xn   = (u16*)(ws + 20971520);         // 10,485,760 bf16
  u16*   qb   = (u16*)(ws + 31457280);         // 10,485,760
  u16*   kb   = (u16*)(ws + 41943040);         // 10,485,760
  u16*   vb   = (u16*)(ws + 52428800);         // 10,485,760
  u16*   big  = (u16*)(ws + 62914560);         // 28,835,840 (attn-out / ffn act)
  u16*   hsb  = (u16*)(ws + 91750400);         // 81,920
  float* part = (float*)(ws + 91832320);       // 1,280,000
  float* lbl  = (float*)(ws + 93112320);       // 320
  u16*   wT   = (u16*)(ws + 93112640);         // 12,845,056

  // ---- weight transpose+convert (bf16 [N][K]); wq carries the 1/sqrt(HD) scale ----
  for (int l = 0; l < kNL; l++) {
    u16* base = wT + (size_t)l * kPL;
    dim3 g512(16, 16);
    k_wtrans<<<g512, 256, 0, stream>>>(wq + (size_t)l * kD * kD, base + oWQ, kD, kD, 0.125f);
    k_wtrans<<<g512, 256, 0, stream>>>(wk + (size_t)l * kD * kD, base + oWK, kD, kD, 1.f);
    k_wtrans<<<g512, 256, 0, stream>>>(wv + (size_t)l * kD * kD, base + oWV, kD, kD, 1.f);
    k_wtrans<<<g512, 256, 0, stream>>>(wo + (size_t)l * kD * kD, base + oWO, kD, kD, 1.f);
    dim3 g13(44, 16);
    k_wtrans<<<g13, 256, 0, stream>>>(w1 + (size_t)l * kD * kHID, base + oW1, kD, kHID, 1.f);
    k_wtrans<<<g13, 256, 0, stream>>>(w3 + (size_t)l * kD * kHID, base + oW3, kD, kHID, 1.f);
    dim3 g2(16, 44);
    k_wtrans<<<g2, 256, 0, stream>>>(w2 + (size_t)l * kHID * kD, base + oW2, kHID, kD, 1.f);
  }

  k_embed<<<kNS, 128, 0, stream>>>(input_ids, label_ids, emb, h);

  for (int l = 0; l < kNL; l++) {
    u16* base = wT + (size_t)l * kPL;
    k_rmsnorm<<<kNS, 256, 0, stream>>>(h, attn_norm_w + (size_t)l * kD, xn);
    k_gemm_bf16<0><<<320, 256, 0, stream>>>(xn, base + oWQ, qb, kNS, kD, kD, 4);
    k_gemm_bf16<0><<<320, 256, 0, stream>>>(xn, base + oWK, kb, kNS, kD, kD, 4);
    k_gemm_bf16<0><<<320, 256, 0, stream>>>(xn, base + oWV, vb, kNS, kD, kD, 4);
    k_rope<<<(kNS * kNH * 16) / 256, 256, 0, stream>>>(qb, kb);
    dim3 gattn(kS / 64, kNSeq * kNH);
    k_attn_mfma<<<gattn, 256, 0, stream>>>(qb, kb, vb, big);
    k_gemm_bf16<1><<<320, 256, 0, stream>>>(big, base + oWO, h, kNS, kD, kD, 4);
    k_rmsnorm<<<kNS, 256, 0, stream>>>(h, ffn_norm_w + (size_t)l * kD, xn);
    k_ffn13_bf16<<<880, 256, 0, stream>>>(xn, base + oW1, base + oW3, big, kNS, kHID, kD, 11);
    k_gemm_bf16<1><<<320, 256, 0, stream>>>(big, base + oW2, h, kNS, kD, kHID, 4);
  }

  k_rmsnorm<<<kNS, 256, 0, stream>>>(h, final_norm_w, xn);
  k_gather<<<kNSeq * kLBL, 128, 0, stream>>>(xn, hsb);
  k_logits_mfma<<<kV / 256, 256, 0, stream>>>(hsb, lm_head, part);
  k_label_logits<<<kNSeq * kLBL, 64, 0, stream>>>(hsb, lm_head, label_ids, lbl);
  k_final<<<kNSeq, 64, 0, stream>>>(part, lbl, out);
}

// Round 6
// 634.340 us; speedup vs baseline: 6.9057x; 1.1876x over previous
//
#include <hip/hip_runtime.h>
#include <math.h>

typedef unsigned short u16;
typedef unsigned int u32;

namespace {
constexpr int kV = 128000, kD = 512, kNH = 8, kNL = 2, kHID = 1408;
constexpr int kHD = 64, kB = 4, kT = 508, kNLAB = 5, kLBL = 4;
constexpr int kS = 512;                 // T + LBL
constexpr int kNSeq = kNLAB * kB;       // 20
constexpr int kNS = kNSeq * kS;         // 10240 rows
constexpr int kQKV = 1536;              // merged qkv row stride
constexpr float kEps = 1e-5f;
constexpr int kNChunk = 2000;           // 64-col partial chunks
constexpr int kPad = 56;                // logits LDS row stride (bf16)
constexpr int kStr = 72;                // attn LDS row stride (bf16)
constexpr int kPL = 3211264;            // per-layer transposed-weight elems
constexpr int oWQ = 0, oWK = 262144, oWV = 524288, oWO = 786432;
constexpr int oW1 = 1048576, oW3 = 1769472, oW2 = 2490368;
}

typedef __attribute__((ext_vector_type(8))) short bf16x8;
typedef __attribute__((ext_vector_type(4))) float f32x4;

__device__ inline u32 pk2(float lo, float hi) {   // RNE fp32->bf16 pair
  u32 ul = __builtin_bit_cast(u32, lo);
  u32 uh = __builtin_bit_cast(u32, hi);
  ul += 0x7fffu + ((ul >> 16) & 1u);
  uh += 0x7fffu + ((uh >> 16) & 1u);
  return (ul >> 16) | (uh & 0xffff0000u);
}
__device__ inline u16 bf1(float x) {
  u32 u = __builtin_bit_cast(u32, x);
  u += 0x7fffu + ((u >> 16) & 1u);
  return (u16)(u >> 16);
}
__device__ inline float bf2f(u16 u) {
  return __builtin_bit_cast(float, ((u32)u) << 16);
}
__device__ inline void gload16(const void* g, void* l) {
  __builtin_amdgcn_global_load_lds(
      (const __attribute__((address_space(1))) void*)g,
      (__attribute__((address_space(3))) void*)l, 16, 0, 0);
}

// ---------------- ALL weight transposes in one launch ----------------
// dst[n][k] = src[k][n]*scale, 32x32 tiles. 3136 tiles/layer x 2 layers.
__global__ __launch_bounds__(256) void k_wtrans_all(const float* __restrict__ wq,
                                                    const float* __restrict__ wk,
                                                    const float* __restrict__ wv,
                                                    const float* __restrict__ wo,
                                                    const float* __restrict__ w1,
                                                    const float* __restrict__ w3,
                                                    const float* __restrict__ w2,
                                                    u16* __restrict__ wT) {
  int bid = blockIdx.x;
  int l = bid / 3136, r = bid % 3136;
  const float* src; u16* dst; int K, N, gxw, t; float scale = 1.f;
  if (r < 1024) {
    int w = r >> 8; t = r & 255; K = 512; N = 512; gxw = 16;
    src = (w == 0 ? wq : w == 1 ? wk : w == 2 ? wv : wo) + (size_t)l * 262144;
    dst = wT + (size_t)l * kPL + w * 262144;
    if (w == 0) scale = 0.125f;
  } else if (r < 2432) {
    int rr = r - 1024; int w = rr / 704; t = rr - w * 704; K = 512; N = 1408; gxw = 44;
    src = (w ? w3 : w1) + (size_t)l * 720896;
    dst = wT + (size_t)l * kPL + (w ? oW3 : oW1);
  } else {
    t = r - 2432; K = 1408; N = 512; gxw = 16;
    src = w2 + (size_t)l * 720896;
    dst = wT + (size_t)l * kPL + oW2;
  }
  int bn = (t % gxw) * 32, bk = (t / gxw) * 32;
  __shared__ float tb[32][33];
  int tid = threadIdx.x;
  int rr2 = tid >> 3, c4 = (tid & 7) * 4;
  float4 v = *(const float4*)(src + (size_t)(bk + rr2) * N + bn + c4);
  tb[rr2][c4 + 0] = v.x * scale; tb[rr2][c4 + 1] = v.y * scale;
  tb[rr2][c4 + 2] = v.z * scale; tb[rr2][c4 + 3] = v.w * scale;
  __syncthreads();
  uint2 o;
  o.x = pk2(tb[c4 + 0][rr2], tb[c4 + 1][rr2]);
  o.y = pk2(tb[c4 + 2][rr2], tb[c4 + 3][rr2]);
  *(uint2*)&dst[(size_t)(bn + rr2) * K + bk + c4] = o;
}

// ---------------- embedding (fp32 h) ----------------
__global__ void k_embed(const int* __restrict__ input_ids, const int* __restrict__ label_ids,
                        const float* __restrict__ emb, float* __restrict__ h) {
  int row = blockIdx.x;
  int n = row / kS, s = row - n * kS;
  int lab = n / kB, b = n - lab * kB;
  int tok = (s < kT) ? input_ids[b * kT + s] : label_ids[lab * kLBL + (s - kT)];
  const float4* src = (const float4*)(emb + (size_t)tok * kD);
  float4* dst = (float4*)(h + (size_t)row * kD);
  for (int i = threadIdx.x; i < kD / 4; i += blockDim.x) dst[i] = src[i];
}

// ---------------- rmsnorm: fp32 in, bf16 out ----------------
__global__ __launch_bounds__(256) void k_rmsnorm(const float* __restrict__ x,
                                                 const float* __restrict__ w,
                                                 u16* __restrict__ y) {
  int row = blockIdx.x;
  int tid = threadIdx.x;
  const float* xr = x + (size_t)row * kD;
  int i = tid * 2;
  float v0 = xr[i], v1 = xr[i + 1];
  float ss = v0 * v0 + v1 * v1;
  #pragma unroll
  for (int o = 1; o < 64; o <<= 1) ss += __shfl_xor(ss, o);
  __shared__ float wsum[4];
  int lane = tid & 63, wid = tid >> 6;
  if (lane == 0) wsum[wid] = ss;
  __syncthreads();
  float tot = wsum[0] + wsum[1] + wsum[2] + wsum[3];
  float inv = rsqrtf(tot / (float)kD + kEps);
  *(u32*)&y[(size_t)row * kD + i] = pk2(v0 * inv * w[i], v1 * inv * w[i + 1]);
}

// ---------------- bf16 MFMA GEMM with global_load_lds staging ----------------
// A[M,K]bf16 @ Bt[N,K]bf16. MODE 0: C bf16 = A@B ; MODE 1: C fp32 += A@B.
// 128x128 tile, 4 waves, BK=64, LDS [4][128][16] per operand (linear for gload_lds).
template<int MODE>
__global__ __launch_bounds__(256) void k_gemm_bf16(const u16* __restrict__ A,
                                                   const u16* __restrict__ Bt,
                                                   void* __restrict__ Cv,
                                                   int M, int N, int K, int gx) {
  __shared__ u16 As[4 * 128 * 16];
  __shared__ u16 Bs[4 * 128 * 16];
  int nwg = gridDim.x;
  int q8 = nwg >> 3;
  int wg = (blockIdx.x & 7) * q8 + (blockIdx.x >> 3);
  int by = wg / gx, bx = wg - by * gx;
  int row0 = by * 128, col0 = bx * 128;
  int tid = threadIdx.x;
  int wave = tid >> 6, lane = tid & 63;
  int wm = wave >> 1, wn = wave & 1;
  int l15 = lane & 15, l16 = lane >> 4;
  f32x4 acc[4][4];
  #pragma unroll
  for (int i = 0; i < 4; i++)
    #pragma unroll
    for (int j = 0; j < 4; j++) acc[i][j] = (f32x4){0.f, 0.f, 0.f, 0.f};

  int sR = lane >> 1, sS = (lane & 1) * 8;   // staging: row-within-32-group, k-sub

  for (int k0 = 0; k0 < K; k0 += 64) {
    // wave stages k-quarter q=wave for both operands; i = 32-row group
    #pragma unroll
    for (int i = 0; i < 4; i++) {
      int rr = i * 32 + sR;
      gload16(A + (size_t)(row0 + rr) * K + k0 + wave * 16 + sS,
              (char*)As + (wave * 4 + i) * 1024);
      gload16(Bt + (size_t)(col0 + rr) * K + k0 + wave * 16 + sS,
              (char*)Bs + (wave * 4 + i) * 1024);
    }
    __syncthreads();
    #pragma unroll
    for (int kk = 0; kk < 2; kk++) {
      int qq = kk * 2 + (l16 >> 1);
      int sub = (l16 & 1) * 8;
      bf16x8 af[4], bfr[4];
      #pragma unroll
      for (int mf = 0; mf < 4; mf++)
        af[mf] = *(const bf16x8*)&As[qq * 2048 + (wm * 64 + mf * 16 + l15) * 16 + sub];
      #pragma unroll
      for (int nf = 0; nf < 4; nf++)
        bfr[nf] = *(const bf16x8*)&Bs[qq * 2048 + (wn * 64 + nf * 16 + l15) * 16 + sub];
      #pragma unroll
      for (int mf = 0; mf < 4; mf++)
        #pragma unroll
        for (int nf = 0; nf < 4; nf++)
          acc[mf][nf] = __builtin_amdgcn_mfma_f32_16x16x32_bf16(af[mf], bfr[nf], acc[mf][nf], 0, 0, 0);
    }
    __syncthreads();
  }
  #pragma unroll
  for (int mf = 0; mf < 4; mf++)
    #pragma unroll
    for (int nf = 0; nf < 4; nf++)
      #pragma unroll
      for (int r = 0; r < 4; r++) {
        int row = row0 + wm * 64 + mf * 16 + l16 * 4 + r;
        int col = col0 + wn * 64 + nf * 16 + l15;
        size_t off = (size_t)row * N + col;
        if (MODE == 1) ((float*)Cv)[off] += acc[mf][nf][r];
        else           ((u16*)Cv)[off] = bf1(acc[mf][nf][r]);
      }
}

// ---------------- FFN dual GEMM (gload_lds staging): act = silu(A@W1)*(A@W3) ----------------
__global__ __launch_bounds__(256) void k_ffn13_bf16(const u16* __restrict__ A,
                                                    const u16* __restrict__ W1t,
                                                    const u16* __restrict__ W3t,
                                                    u16* __restrict__ act,
                                                    int M, int N, int K, int gx) {
  __shared__ u16 As[4 * 128 * 16];
  __shared__ u16 B1[4 * 128 * 16];
  __shared__ u16 B2[4 * 128 * 16];
  int nwg = gridDim.x;
  int q8 = nwg >> 3;
  int wg = (blockIdx.x & 7) * q8 + (blockIdx.x >> 3);
  int by = wg / gx, bx = wg - by * gx;
  int row0 = by * 128, col0 = bx * 128;
  int tid = threadIdx.x;
  int wave = tid >> 6, lane = tid & 63;
  int wm = wave >> 1, wn = wave & 1;
  int l15 = lane & 15, l16 = lane >> 4;
  f32x4 acc1[4][4], acc2[4][4];
  #pragma unroll
  for (int i = 0; i < 4; i++)
    #pragma unroll
    for (int j = 0; j < 4; j++) {
      acc1[i][j] = (f32x4){0.f, 0.f, 0.f, 0.f};
      acc2[i][j] = (f32x4){0.f, 0.f, 0.f, 0.f};
    }
  int sR = lane >> 1, sS = (lane & 1) * 8;

  for (int k0 = 0; k0 < K; k0 += 64) {
    #pragma unroll
    for (int i = 0; i < 4; i++) {
      int rr = i * 32 + sR;
      gload16(A   + (size_t)(row0 + rr) * K + k0 + wave * 16 + sS,
              (char*)As + (wave * 4 + i) * 1024);
      gload16(W1t + (size_t)(col0 + rr) * K + k0 + wave * 16 + sS,
              (char*)B1 + (wave * 4 + i) * 1024);
      gload16(W3t + (size_t)(col0 + rr) * K + k0 + wave * 16 + sS,
              (char*)B2 + (wave * 4 + i) * 1024);
    }
    __syncthreads();
    #pragma unroll
    for (int kk = 0; kk < 2; kk++) {
      int qq = kk * 2 + (l16 >> 1);
      int sub = (l16 & 1) * 8;
      bf16x8 af[4], b1f[4], b2f[4];
      #pragma unroll
      for (int mf = 0; mf < 4; mf++)
        af[mf] = *(const bf16x8*)&As[qq * 2048 + (wm * 64 + mf * 16 + l15) * 16 + sub];
      #pragma unroll
      for (int nf = 0; nf < 4; nf++) {
        b1f[nf] = *(const bf16x8*)&B1[qq * 2048 + (wn * 64 + nf * 16 + l15) * 16 + sub];
        b2f[nf] = *(const bf16x8*)&B2[qq * 2048 + (wn * 64 + nf * 16 + l15) * 16 + sub];
      }
      #pragma unroll
      for (int mf = 0; mf < 4; mf++)
        #pragma unroll
        for (int nf = 0; nf < 4; nf++) {
          acc1[mf][nf] = __builtin_amdgcn_mfma_f32_16x16x32_bf16(af[mf], b1f[nf], acc1[mf][nf], 0, 0, 0);
          acc2[mf][nf] = __builtin_amdgcn_mfma_f32_16x16x32_bf16(af[mf], b2f[nf], acc2[mf][nf], 0, 0, 0);
        }
    }
    __syncthreads();
  }
  #pragma unroll
  for (int mf = 0; mf < 4; mf++)
    #pragma unroll
    for (int nf = 0; nf < 4; nf++)
      #pragma unroll
      for (int r = 0; r < 4; r++) {
        int row = row0 + wm * 64 + mf * 16 + l16 * 4 + r;
        int col = col0 + wn * 64 + nf * 16 + l15;
        float aa = acc1[mf][nf][r];
        float sg = 1.f / (1.f + expf(-aa));
        act[(size_t)row * N + col] = bf1(aa * sg * acc2[mf][nf][r]);
      }
}

// ---------------- RoPE on merged qkv (q at +0, k at +512) ----------------
__global__ void k_rope(u16* __restrict__ qkv) {
  int idx = blockIdx.x * blockDim.x + threadIdx.x;   // kNS*kNH*16
  if (idx >= kNS * kNH * 16) return;
  int d2 = (idx & 15) * 2;
  int t = idx >> 4;
  int hh = t & (kNH - 1);
  int row = t >> 3;
  int s = row & (kS - 1);
  float fa = expf(-0.2878231366242558f * (float)d2);        // 10000^(-d/32)
  float fb = expf(-0.2878231366242558f * (float)(d2 + 1));
  float aa = (float)s * fa, ab = (float)s * fb;
  float ca = cosf(aa), sa = sinf(aa);
  float cb = cosf(ab), sb = sinf(ab);
  size_t base = (size_t)row * kQKV + hh * kHD + d2;
  u32 q1 = *(u32*)&qkv[base], q2 = *(u32*)&qkv[base + 32];
  float x1a = bf2f((u16)q1), x1b = bf2f((u16)(q1 >> 16));
  float x2a = bf2f((u16)q2), x2b = bf2f((u16)(q2 >> 16));
  *(u32*)&qkv[base]      = pk2(x1a * ca - x2a * sa, x1b * cb - x2b * sb);
  *(u32*)&qkv[base + 32] = pk2(x1a * sa + x2a * ca, x1b * sb + x2b * cb);
  u32 k1 = *(u32*)&qkv[base + 512], k2 = *(u32*)&qkv[base + 544];
  x1a = bf2f((u16)k1); x1b = bf2f((u16)(k1 >> 16));
  x2a = bf2f((u16)k2); x2b = bf2f((u16)(k2 >> 16));
  *(u32*)&qkv[base + 512] = pk2(x1a * ca - x2a * sa, x1b * cb - x2b * sb);
  *(u32*)&qkv[base + 544] = pk2(x1a * sa + x2a * ca, x1b * sb + x2b * cb);
}

// ---------------- MFMA flash attention (merged qkv input, q pre-scaled) ----------------
__global__ __launch_bounds__(256) void k_attn_mfma(const u16* __restrict__ qkv,
                                                   u16* __restrict__ o) {
  int qt = blockIdx.x;
  int nh = blockIdx.y;
  int hh = nh & (kNH - 1), n = nh >> 3;
  int tid = threadIdx.x;
  int wq = tid >> 6, lane = tid & 63;
  int l15 = lane & 15, l16 = lane >> 4;
  __shared__ u16 Ks[64 * kStr];        // [kv][hd]
  __shared__ u16 Vt[64 * kStr];        // [hd][kv]
  __shared__ u16 Ps[4][16 * kStr];     // per-wave P [q][kv]
  int q0 = qt * 64;
  int qrow = q0 + wq * 16 + l15;

  bf16x8 qf[2];
  {
    const u16* qg = qkv + (size_t)(n * kS + qrow) * kQKV + hh * kHD;
    qf[0] = *(const bf16x8*)(qg + l16 * 8);
    qf[1] = *(const bf16x8*)(qg + 32 + l16 * 8);
  }

  f32x4 oacc[4];
  #pragma unroll
  for (int i = 0; i < 4; i++) oacc[i] = (f32x4){0.f, 0.f, 0.f, 0.f};
  float m_run = -1e30f, l_run = 0.f;

  int skv = tid & 63, sd0 = (tid >> 6) * 16;

  for (int jt = 0; jt <= qt; jt++) {
    int j0 = jt * 64;
    __syncthreads();
    {
      size_t gb = (size_t)(n * kS + j0 + skv) * kQKV + 512 + hh * kHD + sd0;
      const u16* kg = qkv + gb;
      *(uint4*)&Ks[skv * kStr + sd0]     = *(const uint4*)kg;
      *(uint4*)&Ks[skv * kStr + sd0 + 8] = *(const uint4*)(kg + 8);
      union { uint4 u4[2]; u16 us[16]; } vb;
      vb.u4[0] = *(const uint4*)(kg + 512);
      vb.u4[1] = *(const uint4*)(kg + 520);
      #pragma unroll
      for (int i = 0; i < 16; i++) Vt[(sd0 + i) * kStr + skv] = vb.us[i];
    }
    __syncthreads();

    f32x4 st[4];
    #pragma unroll
    for (int kt = 0; kt < 4; kt++) {
      bf16x8 ka0 = *(const bf16x8*)&Ks[(kt * 16 + l15) * kStr + l16 * 8];
      bf16x8 ka1 = *(const bf16x8*)&Ks[(kt * 16 + l15) * kStr + 32 + l16 * 8];
      f32x4 c = (f32x4){0.f, 0.f, 0.f, 0.f};
      c = __builtin_amdgcn_mfma_f32_16x16x32_bf16(ka0, qf[0], c, 0, 0, 0);
      c = __builtin_amdgcn_mfma_f32_16x16x32_bf16(ka1, qf[1], c, 0, 0, 0);
      st[kt] = c;
    }

    float mx = m_run;
    #pragma unroll
    for (int kt = 0; kt < 4; kt++)
      #pragma unroll
      for (int r = 0; r < 4; r++) {
        int kvg = j0 + kt * 16 + l16 * 4 + r;
        if (kvg > qrow) st[kt][r] = -1e30f;
        mx = fmaxf(mx, st[kt][r]);
      }
    mx = fmaxf(mx, __shfl_xor(mx, 16));
    mx = fmaxf(mx, __shfl_xor(mx, 32));
    float sc = __expf(m_run - mx);
    float p[4][4];
    float rs = 0.f;
    #pragma unroll
    for (int kt = 0; kt < 4; kt++)
      #pragma unroll
      for (int r = 0; r < 4; r++) { p[kt][r] = __expf(st[kt][r] - mx); rs += p[kt][r]; }
    rs += __shfl_xor(rs, 16);
    rs += __shfl_xor(rs, 32);
    l_run = l_run * sc + rs;
    m_run = mx;
    #pragma unroll
    for (int dt = 0; dt < 4; dt++)
      #pragma unroll
      for (int r = 0; r < 4; r++) oacc[dt][r] *= sc;

    #pragma unroll
    for (int kt = 0; kt < 4; kt++) {
      uint2 w2;
      w2.x = pk2(p[kt][0], p[kt][1]);
      w2.y = pk2(p[kt][2], p[kt][3]);
      *(uint2*)&Ps[wq][l15 * kStr + kt * 16 + l16 * 4] = w2;
    }
    asm volatile("s_waitcnt lgkmcnt(0)" ::: "memory");
    __builtin_amdgcn_sched_barrier(0);

    bf16x8 pf0 = *(const bf16x8*)&Ps[wq][l15 * kStr + l16 * 8];
    bf16x8 pf1 = *(const bf16x8*)&Ps[wq][l15 * kStr + 32 + l16 * 8];
    #pragma unroll
    for (int dt = 0; dt < 4; dt++) {
      bf16x8 va0 = *(const bf16x8*)&Vt[(dt * 16 + l15) * kStr + l16 * 8];
      bf16x8 va1 = *(const bf16x8*)&Vt[(dt * 16 + l15) * kStr + 32 + l16 * 8];
      oacc[dt] = __builtin_amdgcn_mfma_f32_16x16x32_bf16(va0, pf0, oacc[dt], 0, 0, 0);
      oacc[dt] = __builtin_amdgcn_mfma_f32_16x16x32_bf16(va1, pf1, oacc[dt], 0, 0, 0);
    }
  }

  float inv = 1.f / l_run;
  u16* og = o + (size_t)(n * kS + qrow) * kD + hh * kHD;
  #pragma unroll
  for (int dt = 0; dt < 4; dt++) {
    uint2 ow;
    ow.x = pk2(oacc[dt][0] * inv, oacc[dt][1] * inv);
    ow.y = pk2(oacc[dt][2] * inv, oacc[dt][3] * inv);
    *(uint2*)(og + dt * 16 + l16 * 4) = ow;
  }
}

// ---------------- gather the 80 scoring rows (bf16) ----------------
__global__ void k_gather(const u16* __restrict__ xn, u16* __restrict__ hs) {
  int r = blockIdx.x;
  int n = r / kLBL, li = r - n * kLBL;
  size_t src = ((size_t)n * kS + (kT - 1 + li)) * kD;
  int i = threadIdx.x;
  *(uint2*)&hs[(size_t)r * kD + i * 4] = *(const uint2*)&xn[src + i * 4];
}

// ---------------- logits partials via MFMA (A bf16, lm fp32 streamed) ----------------
__global__ __launch_bounds__(256) void k_logits_mfma(const u16* __restrict__ hs,
                                                     const float* __restrict__ lm,
                                                     float* __restrict__ part) {
  __shared__ u16 As[80 * kPad];
  __shared__ u16 Bs[256 * kPad];
  int tid = threadIdx.x;
  int wave = tid >> 6, lane = tid & 63;
  int l15 = lane & 15, l16 = lane >> 4;
  int col0 = blockIdx.x * 256;
  f32x4 acc[5][4];
  #pragma unroll
  for (int i = 0; i < 5; i++)
    #pragma unroll
    for (int j = 0; j < 4; j++) acc[i][j] = (f32x4){0.f, 0.f, 0.f, 0.f};

  int arow = tid >> 1, ahalf = tid & 1;
  int bkp = tid >> 4, bf4 = tid & 15;

  for (int k0 = 0; k0 < kD; k0 += 32) {
    if (tid < 160) {
      const u16* ag = hs + (size_t)arow * kD + k0 + ahalf * 16;
      *(uint4*)&As[arow * kPad + ahalf * 16]     = *(const uint4*)ag;
      *(uint4*)&As[arow * kPad + ahalf * 16 + 8] = *(const uint4*)(ag + 8);
    }
    #pragma unroll
    for (int t = 0; t < 4; t++) {
      int colq = bf4 + 16 * t;
      const float* bg = lm + (size_t)(k0 + 2 * bkp) * kV + col0 + colq * 4;
      float4 lo = *(const float4*)bg;
      float4 hi = *(const float4*)(bg + kV);
      *(u32*)&Bs[(colq * 4 + 0) * kPad + 2 * bkp] = pk2(lo.x, hi.x);
      *(u32*)&Bs[(colq * 4 + 1) * kPad + 2 * bkp] = pk2(lo.y, hi.y);
      *(u32*)&Bs[(colq * 4 + 2) * kPad + 2 * bkp] = pk2(lo.z, hi.z);
      *(u32*)&Bs[(colq * 4 + 3) * kPad + 2 * bkp] = pk2(lo.w, hi.w);
    }
    __syncthreads();
    bf16x8 af[5], bfr[4];
    #pragma unroll
    for (int mf = 0; mf < 5; mf++)
      af[mf] = *(const bf16x8*)&As[(mf * 16 + l15) * kPad + l16 * 8];
    #pragma unroll
    for (int nf = 0; nf < 4; nf++)
      bfr[nf] = *(const bf16x8*)&Bs[(wave * 64 + nf * 16 + l15) * kPad + l16 * 8];
    #pragma unroll
    for (int mf = 0; mf < 5; mf++)
      #pragma unroll
      for (int nf = 0; nf < 4; nf++)
        acc[mf][nf] = __builtin_amdgcn_mfma_f32_16x16x32_bf16(af[mf], bfr[nf], acc[mf][nf], 0, 0, 0);
    __syncthreads();
  }

  int chunk = blockIdx.x * 4 + wave;
  #pragma unroll
  for (int mf = 0; mf < 5; mf++)
    #pragma unroll
    for (int r = 0; r < 4; r++) {
      float mx = fmaxf(fmaxf(acc[mf][0][r], acc[mf][1][r]),
                       fmaxf(acc[mf][2][r], acc[mf][3][r]));
      #pragma unroll
      for (int off = 1; off < 16; off <<= 1) mx = fmaxf(mx, __shfl_xor(mx, off));
      float se = expf(acc[mf][0][r] - mx) + expf(acc[mf][1][r] - mx) +
                 expf(acc[mf][2][r] - mx) + expf(acc[mf][3][r] - mx);
      #pragma unroll
      for (int off = 1; off < 16; off <<= 1) se += __shfl_xor(se, off);
      if (l15 == 0) {
        int row = mf * 16 + l16 * 4 + r;
        size_t pi = ((size_t)row * kNChunk + chunk) * 2;
        part[pi] = mx; part[pi + 1] = se;
      }
    }
}

// ---------------- label-token logits ----------------
__global__ __launch_bounds__(64) void k_label_logits(const u16* __restrict__ hs,
                                                     const float* __restrict__ lm,
                                                     const int* __restrict__ label_ids,
                                                     float* __restrict__ lbl) {
  int r = blockIdx.x;
  int li = r & 3, n = r >> 2, lab = n / kB;
  int tok = label_ids[lab * kLBL + li];
  int lane = threadIdx.x;
  float dv = 0.f;
  for (int d2 = lane; d2 < kD; d2 += 64)
    dv += bf2f(hs[(size_t)r * kD + d2]) * lm[(size_t)d2 * kV + tok];
  #pragma unroll
  for (int o2 = 1; o2 < 64; o2 <<= 1) dv += __shfl_xor(dv, o2);
  if (lane == 0) lbl[r] = dv;
}

// ---------------- final reduce ----------------
__global__ __launch_bounds__(64) void k_final(const float* __restrict__ part,
                                              const float* __restrict__ lbl,
                                              float* __restrict__ out) {
  int n = blockIdx.x;
  int lab = n / kB, b = n - lab * kB;
  int lane = threadIdx.x;
  float res = 0.f;
  for (int li = 0; li < kLBL; li++) {
    int r = n * kLBL + li;
    const float* pr = part + (size_t)r * kNChunk * 2;
    float mx = -1e30f;
    for (int c = lane; c < kNChunk; c += 64) mx = fmaxf(mx, pr[c * 2]);
    #pragma unroll
    for (int o2 = 1; o2 < 64; o2 <<= 1) mx = fmaxf(mx, __shfl_xor(mx, o2));
    float sum = 0.f;
    for (int c = lane; c < kNChunk; c += 64) sum += pr[c * 2 + 1] * expf(pr[c * 2] - mx);
    #pragma unroll
    for (int o2 = 1; o2 < 64; o2 <<= 1) sum += __shfl_xor(sum, o2);
    res += lbl[r] - (mx + logf(sum));
  }
  if (lane == 0) out[b * kNLAB + lab] = res;
}

extern "C" void kernel_launch(void* const* d_in, const int* in_sizes, int n_in,
                              void* d_out, int out_size, void* d_ws, size_t ws_size,
                              hipStream_t stream) {
  const int*   input_ids    = (const int*)d_in[0];
  const int*   label_ids    = (const int*)d_in[1];
  const float* emb          = (const float*)d_in[2];
  const float* wq           = (const float*)d_in[3];
  const float* wk           = (const float*)d_in[4];
  const float* wv           = (const float*)d_in[5];
  const float* wo           = (const float*)d_in[6];
  const float* w1           = (const float*)d_in[7];
  const float* w2           = (const float*)d_in[8];
  const float* w3           = (const float*)d_in[9];
  const float* attn_norm_w  = (const float*)d_in[10];
  const float* ffn_norm_w   = (const float*)d_in[11];
  const float* final_norm_w = (const float*)d_in[12];
  const float* lm_head      = (const float*)d_in[13];
  float* out = (float*)d_out;

  char* ws = (char*)d_ws;
  float* h    = (float*)(ws);                  // 20,971,520 B fp32
  u16*   xn   = (u16*)(ws + 20971520);         // 10,485,760 bf16
  u16*   qkv  = (u16*)(ws + 31457280);         // 31,457,280 bf16 [kNS][1536]
  u16*   big  = (u16*)(ws + 62914560);         // 28,835,840 (attn-out / ffn act)
  u16*   hsb  = (u16*)(ws + 91750400);         // 81,920
  float* part = (float*)(ws + 91832320);       // 1,280,000
  float* lbl  = (float*)(ws + 93112320);       // 320
  u16*   wT   = (u16*)(ws + 93112640);         // 12,845,056

  k_wtrans_all<<<2 * 3136, 256, 0, stream>>>(wq, wk, wv, wo, w1, w3, w2, wT);
  k_embed<<<kNS, 128, 0, stream>>>(input_ids, label_ids, emb, h);

  for (int l = 0; l < kNL; l++) {
    u16* base = wT + (size_t)l * kPL;
    k_rmsnorm<<<kNS, 256, 0, stream>>>(h, attn_norm_w + (size_t)l * kD, xn);
    k_gemm_bf16<0><<<960, 256, 0, stream>>>(xn, base + oWQ, qkv, kNS, kQKV, kD, 12);
    k_rope<<<(kNS * kNH * 16) / 256, 256, 0, stream>>>(qkv);
    dim3 gattn(kS / 64, kNSeq * kNH);
    k_attn_mfma<<<gattn, 256, 0, stream>>>(qkv, big);
    k_gemm_bf16<1><<<320, 256, 0, stream>>>(big, base + oWO, h, kNS, kD, kD, 4);
    k_rmsnorm<<<kNS, 256, 0, stream>>>(h, ffn_norm_w + (size_t)l * kD, xn);
    k_ffn13_bf16<<<880, 256, 0, stream>>>(xn, base + oW1, base + oW3, big, kNS, kHID, kD, 11);
    k_gemm_bf16<1><<<320, 256, 0, stream>>>(big, base + oW2, h, kNS, kD, kHID, 4);
  }

  k_rmsnorm<<<kNS, 256, 0, stream>>>(h, final_norm_w, xn);
  k_gather<<<kNSeq * kLBL, 128, 0, stream>>>(xn, hsb);
  k_logits_mfma<<<kV / 256, 256, 0, stream>>>(hsb, lm_head, part);
  k_label_logits<<<kNSeq * kLBL, 64, 0, stream>>>(hsb, lm_head, label_ids, lbl);
  k_final<<<kNSeq, 64, 0, stream>>>(part, lbl, out);
}

// Round 8
// 528.780 us; speedup vs baseline: 8.2843x; 1.1996x over previous
//
#include <hip/hip_runtime.h>
#include <math.h>

typedef unsigned short u16;
typedef unsigned int u32;

namespace {
constexpr int kV = 128000, kD = 512, kNH = 8, kNL = 2, kHID = 1408;
constexpr int kHD = 64, kB = 4, kT = 508, kNLAB = 5, kLBL = 4;
constexpr int kS = 512;                 // T + LBL
constexpr int kNSeq = kNLAB * kB;       // 20
constexpr int kNS = kNSeq * kS;         // 10240 rows
constexpr int kQKV = 1536;              // merged qkv row stride
constexpr float kEps = 1e-5f;
constexpr int kNChunk = 2000;           // 64-col partial chunks
constexpr int kPad = 56;                // logits LDS row stride (bf16)
constexpr int kStr = 72;                // attn LDS row stride (bf16)
constexpr int kPL = 3211264;            // per-layer transposed-weight elems
constexpr int oWQ = 0, oWK = 262144, oWV = 524288, oWO = 786432;
constexpr int oW1 = 1048576, oW3 = 1769472, oW2 = 2490368;
}

typedef __attribute__((ext_vector_type(8))) short bf16x8;
typedef __attribute__((ext_vector_type(4))) float f32x4;

__device__ inline u32 pk2(float lo, float hi) {   // RNE fp32->bf16 pair
  u32 ul = __builtin_bit_cast(u32, lo);
  u32 uh = __builtin_bit_cast(u32, hi);
  ul += 0x7fffu + ((ul >> 16) & 1u);
  uh += 0x7fffu + ((uh >> 16) & 1u);
  return (ul >> 16) | (uh & 0xffff0000u);
}
__device__ inline u16 bf1(float x) {
  u32 u = __builtin_bit_cast(u32, x);
  u += 0x7fffu + ((u >> 16) & 1u);
  return (u16)(u >> 16);
}
__device__ inline float bf2f(u16 u) {
  return __builtin_bit_cast(float, ((u32)u) << 16);
}
__device__ inline void gload16(const void* g, void* l) {
  __builtin_amdgcn_global_load_lds(
      (const __attribute__((address_space(1))) void*)g,
      (__attribute__((address_space(3))) void*)l, 16, 0, 0);
}
// tiled operand index: [row>>7 panel][k>>6 ktile][(kq*2+slot)][row&127][k&7]
__device__ inline size_t tix(int Kt, int row, int k) {
  return ((size_t)(row >> 7) * Kt + (k >> 6)) * 8192 +
         ((((k >> 4) & 3) * 2 + ((k >> 3) & 1)) * 128 + (row & 127)) * 8 + (k & 7);
}

// ---------------- ALL weight transposes in one launch (tiled output) ----------------
__global__ __launch_bounds__(256) void k_wtrans_all(const float* __restrict__ wq,
                                                    const float* __restrict__ wk,
                                                    const float* __restrict__ wv,
                                                    const float* __restrict__ wo,
                                                    const float* __restrict__ w1,
                                                    const float* __restrict__ w3,
                                                    const float* __restrict__ w2,
                                                    u16* __restrict__ wT) {
  int bid = blockIdx.x;
  int l = bid / 3136, r = bid % 3136;
  const float* src; u16* dst; int K, N, gxw, t; float scale = 1.f;
  if (r < 1024) {
    int w = r >> 8; t = r & 255; K = 512; N = 512; gxw = 16;
    src = (w == 0 ? wq : w == 1 ? wk : w == 2 ? wv : wo) + (size_t)l * 262144;
    dst = wT + (size_t)l * kPL + w * 262144;
    if (w == 0) scale = 0.125f;
  } else if (r < 2432) {
    int rr = r - 1024; int w = rr / 704; t = rr - w * 704; K = 512; N = 1408; gxw = 44;
    src = (w ? w3 : w1) + (size_t)l * 720896;
    dst = wT + (size_t)l * kPL + (w ? oW3 : oW1);
  } else {
    t = r - 2432; K = 1408; N = 512; gxw = 16;
    src = w2 + (size_t)l * 720896;
    dst = wT + (size_t)l * kPL + oW2;
  }
  int bn = (t % gxw) * 32, bk = (t / gxw) * 32;
  __shared__ float tb[32][33];
  int tid = threadIdx.x;
  int rr2 = tid >> 3, c4 = (tid & 7) * 4;
  float4 v = *(const float4*)(src + (size_t)(bk + rr2) * N + bn + c4);
  tb[rr2][c4 + 0] = v.x * scale; tb[rr2][c4 + 1] = v.y * scale;
  tb[rr2][c4 + 2] = v.z * scale; tb[rr2][c4 + 3] = v.w * scale;
  __syncthreads();
  uint2 o;
  o.x = pk2(tb[c4 + 0][rr2], tb[c4 + 1][rr2]);
  o.y = pk2(tb[c4 + 2][rr2], tb[c4 + 3][rr2]);
  *(uint2*)&dst[tix(K >> 6, bn + rr2, bk + c4)] = o;
}

// ---------------- embedding (fp32 h) ----------------
__global__ void k_embed(const int* __restrict__ input_ids, const int* __restrict__ label_ids,
                        const float* __restrict__ emb, float* __restrict__ h) {
  int row = blockIdx.x;
  int n = row / kS, s = row - n * kS;
  int lab = n / kB, b = n - lab * kB;
  int tok = (s < kT) ? input_ids[b * kT + s] : label_ids[lab * kLBL + (s - kT)];
  const float4* src = (const float4*)(emb + (size_t)tok * kD);
  float4* dst = (float4*)(h + (size_t)row * kD);
  for (int i = threadIdx.x; i < kD / 4; i += blockDim.x) dst[i] = src[i];
}

// ---------------- rmsnorm: fp32 in, bf16 TILED out (K=512 -> Kt=8) ----------------
__global__ __launch_bounds__(256) void k_rmsnorm(const float* __restrict__ x,
                                                 const float* __restrict__ w,
                                                 u16* __restrict__ y) {
  int row = blockIdx.x;
  int tid = threadIdx.x;
  const float* xr = x + (size_t)row * kD;
  int i = tid * 2;
  float v0 = xr[i], v1 = xr[i + 1];
  float ss = v0 * v0 + v1 * v1;
  #pragma unroll
  for (int o = 1; o < 64; o <<= 1) ss += __shfl_xor(ss, o);
  __shared__ float wsum[4];
  int lane = tid & 63, wid = tid >> 6;
  if (lane == 0) wsum[wid] = ss;
  __syncthreads();
  float tot = wsum[0] + wsum[1] + wsum[2] + wsum[3];
  float inv = rsqrtf(tot / (float)kD + kEps);
  *(u32*)&y[tix(8, row, i)] = pk2(v0 * inv * w[i], v1 * inv * w[i + 1]);
}

// ---------------- QKV GEMM (tiled A,B) with fused RoPE epilogue ----------------
// M=10240, N=1536, K=512. 128x128 tile, 960 blocks (gx=12), 4 waves.
__global__ __launch_bounds__(256) void k_gemm_qkv(const u16* __restrict__ A,
                                                  const u16* __restrict__ Bt,
                                                  u16* __restrict__ qkv) {
  __shared__ u16 As[8192];
  __shared__ u16 Bs[8192];
  int wg = (blockIdx.x & 7) * 120 + (blockIdx.x >> 3);
  int by = wg / 12, bx = wg - by * 12;
  int row0 = by * 128, col0 = bx * 128;
  int tid = threadIdx.x;
  int wave = tid >> 6, lane = tid & 63;
  int wm = wave >> 1, wn = wave & 1;
  int l15 = lane & 15, l16 = lane >> 4;
  f32x4 acc[4][4];
  #pragma unroll
  for (int i = 0; i < 4; i++)
    #pragma unroll
    for (int j = 0; j < 4; j++) acc[i][j] = (f32x4){0.f, 0.f, 0.f, 0.f};

  for (int kt = 0; kt < 8; kt++) {
    const u16* Ab = A  + ((size_t)(row0 >> 7) * 8 + kt) * 8192;
    const u16* Bb = Bt + ((size_t)(col0 >> 7) * 8 + kt) * 8192;
    #pragma unroll
    for (int i = 0; i < 4; i++) {
      int off = ((wave * 2 + (i >> 1)) * 128 + (i & 1) * 64) * 8;
      gload16(Ab + off + (size_t)lane * 8, (char*)As + off * 2);
      gload16(Bb + off + (size_t)lane * 8, (char*)Bs + off * 2);
    }
    __syncthreads();
    #pragma unroll
    for (int h = 0; h < 2; h++) {
      bf16x8 af[4], bfr[4];
      #pragma unroll
      for (int mf = 0; mf < 4; mf++)
        af[mf] = *(const bf16x8*)&As[((h * 4 + l16) * 128 + wm * 64 + mf * 16 + l15) * 8];
      #pragma unroll
      for (int nf = 0; nf < 4; nf++)
        bfr[nf] = *(const bf16x8*)&Bs[((h * 4 + l16) * 128 + wn * 64 + nf * 16 + l15) * 8];
      #pragma unroll
      for (int mf = 0; mf < 4; mf++)
        #pragma unroll
        for (int nf = 0; nf < 4; nf++)
          acc[mf][nf] = __builtin_amdgcn_mfma_f32_16x16x32_bf16(af[mf], bfr[nf], acc[mf][nf], 0, 0, 0);
    }
    __syncthreads();
  }

  if (bx < 8) {      // q or k: apply RoPE to pairs (d, d+32), d = nf*16+l15, nf in {0,1}
    #pragma unroll
    for (int nf = 0; nf < 2; nf++) {
      int d = nf * 16 + l15;
      float fr = __expf(-0.2878231366242558f * (float)d);    // 10000^(-d/32)
      #pragma unroll
      for (int mf = 0; mf < 4; mf++)
        #pragma unroll
        for (int r = 0; r < 4; r++) {
          int row = row0 + wm * 64 + mf * 16 + l16 * 4 + r;
          int s = row & (kS - 1);
          float sn, cs;
          __sincosf((float)s * fr, &sn, &cs);
          float x1 = acc[mf][nf][r], x2 = acc[mf][nf + 2][r];
          size_t base = (size_t)row * kQKV + col0 + wn * 64 + nf * 16 + l15;
          qkv[base]      = bf1(x1 * cs - x2 * sn);
          qkv[base + 32] = bf1(x1 * sn + x2 * cs);
        }
    }
  } else {           // v: plain store
    #pragma unroll
    for (int mf = 0; mf < 4; mf++)
      #pragma unroll
      for (int nf = 0; nf < 4; nf++)
        #pragma unroll
        for (int r = 0; r < 4; r++) {
          int row = row0 + wm * 64 + mf * 16 + l16 * 4 + r;
          qkv[(size_t)row * kQKV + col0 + wn * 64 + nf * 16 + l15] = bf1(acc[mf][nf][r]);
        }
  }
}

// ---------------- 128x64-tile GEMM (tiled A,B), C fp32 += A@B ----------------
// grid 640 (gx=8), 4 waves stacked on M (wave rows = 32).
__global__ __launch_bounds__(256) void k_gemm_n64(const u16* __restrict__ A,
                                                  const u16* __restrict__ Bt,
                                                  float* __restrict__ C,
                                                  int Kt, int N) {
  __shared__ u16 As[8192];
  __shared__ u16 Bs[4096];
  int nwg = gridDim.x;
  int wg = (blockIdx.x & 7) * (nwg >> 3) + (blockIdx.x >> 3);
  int by = wg >> 3, bx = wg & 7;
  int row0 = by * 128, col0 = bx * 64;
  int p = col0 >> 7, half = (col0 >> 6) & 1;
  int tid = threadIdx.x;
  int wave = tid >> 6, lane = tid & 63;
  int l15 = lane & 15, l16 = lane >> 4;
  f32x4 acc[2][4];
  #pragma unroll
  for (int i = 0; i < 2; i++)
    #pragma unroll
    for (int j = 0; j < 4; j++) acc[i][j] = (f32x4){0.f, 0.f, 0.f, 0.f};

  for (int kt = 0; kt < Kt; kt++) {
    const u16* Ab = A  + ((size_t)(row0 >> 7) * Kt + kt) * 8192;
    const u16* Bb = Bt + ((size_t)p * Kt + kt) * 8192;
    #pragma unroll
    for (int i = 0; i < 4; i++) {
      int off = ((wave * 2 + (i >> 1)) * 128 + (i & 1) * 64) * 8;
      gload16(Ab + off + (size_t)lane * 8, (char*)As + off * 2);
    }
    #pragma unroll
    for (int sl = 0; sl < 2; sl++) {
      int ch = wave * 2 + sl;
      gload16(Bb + (ch * 128 + half * 64) * 8 + (size_t)lane * 8,
              (char*)Bs + (ch * 64) * 16);
    }
    __syncthreads();
    #pragma unroll
    for (int h = 0; h < 2; h++) {
      bf16x8 af[2], bfr[4];
      #pragma unroll
      for (int mf = 0; mf < 2; mf++)
        af[mf] = *(const bf16x8*)&As[((h * 4 + l16) * 128 + wave * 32 + mf * 16 + l15) * 8];
      #pragma unroll
      for (int nf = 0; nf < 4; nf++)
        bfr[nf] = *(const bf16x8*)&Bs[((h * 4 + l16) * 64 + nf * 16 + l15) * 8];
      #pragma unroll
      for (int mf = 0; mf < 2; mf++)
        #pragma unroll
        for (int nf = 0; nf < 4; nf++)
          acc[mf][nf] = __builtin_amdgcn_mfma_f32_16x16x32_bf16(af[mf], bfr[nf], acc[mf][nf], 0, 0, 0);
    }
    __syncthreads();
  }
  #pragma unroll
  for (int mf = 0; mf < 2; mf++)
    #pragma unroll
    for (int nf = 0; nf < 4; nf++)
      #pragma unroll
      for (int r = 0; r < 4; r++) {
        int row = row0 + wave * 32 + mf * 16 + l16 * 4 + r;
        int col = col0 + nf * 16 + l15;
        C[(size_t)row * N + col] += acc[mf][nf][r];
      }
}

// ---------------- FFN dual GEMM (tiled A,B1,B3): act(tiled,Kt=22) = silu(A@W1)*(A@W3) ----------------
__global__ __launch_bounds__(256) void k_ffn13_bf16(const u16* __restrict__ A,
                                                    const u16* __restrict__ W1t,
                                                    const u16* __restrict__ W3t,
                                                    u16* __restrict__ act) {
  __shared__ u16 As[8192];
  __shared__ u16 B1[8192];
  __shared__ u16 B2[8192];
  int wg = (blockIdx.x & 7) * 110 + (blockIdx.x >> 3);
  int by = wg / 11, bx = wg - by * 11;
  int row0 = by * 128, col0 = bx * 128;
  int tid = threadIdx.x;
  int wave = tid >> 6, lane = tid & 63;
  int wm = wave >> 1, wn = wave & 1;
  int l15 = lane & 15, l16 = lane >> 4;
  f32x4 acc1[4][4], acc2[4][4];
  #pragma unroll
  for (int i = 0; i < 4; i++)
    #pragma unroll
    for (int j = 0; j < 4; j++) {
      acc1[i][j] = (f32x4){0.f, 0.f, 0.f, 0.f};
      acc2[i][j] = (f32x4){0.f, 0.f, 0.f, 0.f};
    }

  for (int kt = 0; kt < 8; kt++) {
    const u16* Ab  = A   + ((size_t)(row0 >> 7) * 8 + kt) * 8192;
    const u16* B1b = W1t + ((size_t)(col0 >> 7) * 8 + kt) * 8192;
    const u16* B3b = W3t + ((size_t)(col0 >> 7) * 8 + kt) * 8192;
    #pragma unroll
    for (int i = 0; i < 4; i++) {
      int off = ((wave * 2 + (i >> 1)) * 128 + (i & 1) * 64) * 8;
      gload16(Ab  + off + (size_t)lane * 8, (char*)As + off * 2);
      gload16(B1b + off + (size_t)lane * 8, (char*)B1 + off * 2);
      gload16(B3b + off + (size_t)lane * 8, (char*)B2 + off * 2);
    }
    __syncthreads();
    #pragma unroll
    for (int h = 0; h < 2; h++) {
      bf16x8 af[4], b1f[4], b2f[4];
      #pragma unroll
      for (int mf = 0; mf < 4; mf++)
        af[mf] = *(const bf16x8*)&As[((h * 4 + l16) * 128 + wm * 64 + mf * 16 + l15) * 8];
      #pragma unroll
      for (int nf = 0; nf < 4; nf++) {
        b1f[nf] = *(const bf16x8*)&B1[((h * 4 + l16) * 128 + wn * 64 + nf * 16 + l15) * 8];
        b2f[nf] = *(const bf16x8*)&B2[((h * 4 + l16) * 128 + wn * 64 + nf * 16 + l15) * 8];
      }
      #pragma unroll
      for (int mf = 0; mf < 4; mf++)
        #pragma unroll
        for (int nf = 0; nf < 4; nf++) {
          acc1[mf][nf] = __builtin_amdgcn_mfma_f32_16x16x32_bf16(af[mf], b1f[nf], acc1[mf][nf], 0, 0, 0);
          acc2[mf][nf] = __builtin_amdgcn_mfma_f32_16x16x32_bf16(af[mf], b2f[nf], acc2[mf][nf], 0, 0, 0);
        }
    }
    __syncthreads();
  }
  #pragma unroll
  for (int mf = 0; mf < 4; mf++)
    #pragma unroll
    for (int nf = 0; nf < 4; nf++)
      #pragma unroll
      for (int r = 0; r < 4; r++) {
        int row = row0 + wm * 64 + mf * 16 + l16 * 4 + r;
        int col = col0 + wn * 64 + nf * 16 + l15;
        float aa = acc1[mf][nf][r];
        float sg = 1.f / (1.f + __expf(-aa));
        act[tix(22, row, col)] = bf1(aa * sg * acc2[mf][nf][r]);
      }
}

// ---------------- MFMA flash attention (qkv plain in, TILED out for wo's A) ----------------
__global__ __launch_bounds__(256) void k_attn_mfma(const u16* __restrict__ qkv,
                                                   u16* __restrict__ o) {
  int qt = blockIdx.x;
  int nh = blockIdx.y;
  int hh = nh & (kNH - 1), n = nh >> 3;
  int tid = threadIdx.x;
  int wq = tid >> 6, lane = tid & 63;
  int l15 = lane & 15, l16 = lane >> 4;
  __shared__ u16 Ks[64 * kStr];        // [kv][hd]
  __shared__ u16 Vt[64 * kStr];        // [hd][kv]
  __shared__ u16 Ps[4][16 * kStr];     // per-wave P [q][kv]
  int q0 = qt * 64;
  int qrow = q0 + wq * 16 + l15;

  bf16x8 qf[2];
  {
    const u16* qg = qkv + (size_t)(n * kS + qrow) * kQKV + hh * kHD;
    qf[0] = *(const bf16x8*)(qg + l16 * 8);
    qf[1] = *(const bf16x8*)(qg + 32 + l16 * 8);
  }

  f32x4 oacc[4];
  #pragma unroll
  for (int i = 0; i < 4; i++) oacc[i] = (f32x4){0.f, 0.f, 0.f, 0.f};
  float m_run = -1e30f, l_run = 0.f;

  int skv = tid & 63, sd0 = (tid >> 6) * 16;

  for (int jt = 0; jt <= qt; jt++) {
    int j0 = jt * 64;
    __syncthreads();
    {
      size_t gb = (size_t)(n * kS + j0 + skv) * kQKV + 512 + hh * kHD + sd0;
      const u16* kg = qkv + gb;
      *(uint4*)&Ks[skv * kStr + sd0]     = *(const uint4*)kg;
      *(uint4*)&Ks[skv * kStr + sd0 + 8] = *(const uint4*)(kg + 8);
      union { uint4 u4[2]; u16 us[16]; } vb;
      vb.u4[0] = *(const uint4*)(kg + 512);
      vb.u4[1] = *(const uint4*)(kg + 520);
      #pragma unroll
      for (int i = 0; i < 16; i++) Vt[(sd0 + i) * kStr + skv] = vb.us[i];
    }
    __syncthreads();

    f32x4 st[4];
    #pragma unroll
    for (int kt = 0; kt < 4; kt++) {
      bf16x8 ka0 = *(const bf16x8*)&Ks[(kt * 16 + l15) * kStr + l16 * 8];
      bf16x8 ka1 = *(const bf16x8*)&Ks[(kt * 16 + l15) * kStr + 32 + l16 * 8];
      f32x4 c = (f32x4){0.f, 0.f, 0.f, 0.f};
      c = __builtin_amdgcn_mfma_f32_16x16x32_bf16(ka0, qf[0], c, 0, 0, 0);
      c = __builtin_amdgcn_mfma_f32_16x16x32_bf16(ka1, qf[1], c, 0, 0, 0);
      st[kt] = c;
    }

    float mx = m_run;
    #pragma unroll
    for (int kt = 0; kt < 4; kt++)
      #pragma unroll
      for (int r = 0; r < 4; r++) {
        int kvg = j0 + kt * 16 + l16 * 4 + r;
        if (kvg > qrow) st[kt][r] = -1e30f;
        mx = fmaxf(mx, st[kt][r]);
      }
    mx = fmaxf(mx, __shfl_xor(mx, 16));
    mx = fmaxf(mx, __shfl_xor(mx, 32));
    float sc = __expf(m_run - mx);
    float p[4][4];
    float rs = 0.f;
    #pragma unroll
    for (int kt = 0; kt < 4; kt++)
      #pragma unroll
      for (int r = 0; r < 4; r++) { p[kt][r] = __expf(st[kt][r] - mx); rs += p[kt][r]; }
    rs += __shfl_xor(rs, 16);
    rs += __shfl_xor(rs, 32);
    l_run = l_run * sc + rs;
    m_run = mx;
    #pragma unroll
    for (int dt = 0; dt < 4; dt++)
      #pragma unroll
      for (int r = 0; r < 4; r++) oacc[dt][r] *= sc;

    #pragma unroll
    for (int kt = 0; kt < 4; kt++) {
      uint2 w2;
      w2.x = pk2(p[kt][0], p[kt][1]);
      w2.y = pk2(p[kt][2], p[kt][3]);
      *(uint2*)&Ps[wq][l15 * kStr + kt * 16 + l16 * 4] = w2;
    }
    asm volatile("s_waitcnt lgkmcnt(0)" ::: "memory");
    __builtin_amdgcn_sched_barrier(0);

    bf16x8 pf0 = *(const bf16x8*)&Ps[wq][l15 * kStr + l16 * 8];
    bf16x8 pf1 = *(const bf16x8*)&Ps[wq][l15 * kStr + 32 + l16 * 8];
    #pragma unroll
    for (int dt = 0; dt < 4; dt++) {
      bf16x8 va0 = *(const bf16x8*)&Vt[(dt * 16 + l15) * kStr + l16 * 8];
      bf16x8 va1 = *(const bf16x8*)&Vt[(dt * 16 + l15) * kStr + 32 + l16 * 8];
      oacc[dt] = __builtin_amdgcn_mfma_f32_16x16x32_bf16(va0, pf0, oacc[dt], 0, 0, 0);
      oacc[dt] = __builtin_amdgcn_mfma_f32_16x16x32_bf16(va1, pf1, oacc[dt], 0, 0, 0);
    }
  }

  // tiled store: k = hh*64 + dt*16 + l16*4 -> panel (row>>7), ktile hh
  float inv = 1.f / l_run;
  int rowIdx = n * kS + qrow;
  #pragma unroll
  for (int dt = 0; dt < 4; dt++) {
    uint2 ow;
    ow.x = pk2(oacc[dt][0] * inv, oacc[dt][1] * inv);
    ow.y = pk2(oacc[dt][2] * inv, oacc[dt][3] * inv);
    size_t base = ((size_t)(rowIdx >> 7) * 8 + hh) * 8192 +
                  (size_t)(((dt * 2 + ((l16 >> 1) & 1)) * 128 + (rowIdx & 127)) * 8 + (l16 & 1) * 4);
    *(uint2*)&o[base] = ow;
  }
}

// ---------------- final rmsnorm + gather: only the 80 scoring rows ----------------
__global__ __launch_bounds__(256) void k_rms_gather(const float* __restrict__ x,
                                                    const float* __restrict__ w,
                                                    u16* __restrict__ hs) {
  int r = blockIdx.x;                       // 0..79
  int n = r >> 2, li = r & 3;
  int row = n * kS + (kT - 1 + li);
  int tid = threadIdx.x;
  const float* xr = x + (size_t)row * kD;
  int i = tid * 2;
  float v0 = xr[i], v1 = xr[i + 1];
  float ss = v0 * v0 + v1 * v1;
  #pragma unroll
  for (int o = 1; o < 64; o <<= 1) ss += __shfl_xor(ss, o);
  __shared__ float wsum[4];
  int lane = tid & 63, wid = tid >> 6;
  if (lane == 0) wsum[wid] = ss;
  __syncthreads();
  float tot = wsum[0] + wsum[1] + wsum[2] + wsum[3];
  float inv = rsqrtf(tot / (float)kD + kEps);
  *(u32*)&hs[(size_t)r * kD + i] = pk2(v0 * inv * w[i], v1 * inv * w[i + 1]);
}

// ---------------- logits partials via MFMA (A bf16 plain, lm fp32 streamed) ----------------
__global__ __launch_bounds__(256) void k_logits_mfma(const u16* __restrict__ hs,
                                                     const float* __restrict__ lm,
                                                     float* __restrict__ part) {
  __shared__ u16 As[80 * kPad];
  __shared__ u16 Bs[256 * kPad];
  int tid = threadIdx.x;
  int wave = tid >> 6, lane = tid & 63;
  int l15 = lane & 15, l16 = lane >> 4;
  int col0 = blockIdx.x * 256;
  f32x4 acc[5][4];
  #pragma unroll
  for (int i = 0; i < 5; i++)
    #pragma unroll
    for (int j = 0; j < 4; j++) acc[i][j] = (f32x4){0.f, 0.f, 0.f, 0.f};

  int arow = tid >> 1, ahalf = tid & 1;
  int bkp = tid >> 4, bf4 = tid & 15;

  for (int k0 = 0; k0 < kD; k0 += 32) {
    if (tid < 160) {
      const u16* ag = hs + (size_t)arow * kD + k0 + ahalf * 16;
      *(uint4*)&As[arow * kPad + ahalf * 16]     = *(const uint4*)ag;
      *(uint4*)&As[arow * kPad + ahalf * 16 + 8] = *(const uint4*)(ag + 8);
    }
    #pragma unroll
    for (int t = 0; t < 4; t++) {
      int colq = bf4 + 16 * t;
      const float* bg = lm + (size_t)(k0 + 2 * bkp) * kV + col0 + colq * 4;
      float4 lo = *(const float4*)bg;
      float4 hi = *(const float4*)(bg + kV);
      *(u32*)&Bs[(colq * 4 + 0) * kPad + 2 * bkp] = pk2(lo.x, hi.x);
      *(u32*)&Bs[(colq * 4 + 1) * kPad + 2 * bkp] = pk2(lo.y, hi.y);
      *(u32*)&Bs[(colq * 4 + 2) * kPad + 2 * bkp] = pk2(lo.z, hi.z);
      *(u32*)&Bs[(colq * 4 + 3) * kPad + 2 * bkp] = pk2(lo.w, hi.w);
    }
    __syncthreads();
    bf16x8 af[5], bfr[4];
    #pragma unroll
    for (int mf = 0; mf < 5; mf++)
      af[mf] = *(const bf16x8*)&As[(mf * 16 + l15) * kPad + l16 * 8];
    #pragma unroll
    for (int nf = 0; nf < 4; nf++)
      bfr[nf] = *(const bf16x8*)&Bs[(wave * 64 + nf * 16 + l15) * kPad + l16 * 8];
    #pragma unroll
    for (int mf = 0; mf < 5; mf++)
      #pragma unroll
      for (int nf = 0; nf < 4; nf++)
        acc[mf][nf] = __builtin_amdgcn_mfma_f32_16x16x32_bf16(af[mf], bfr[nf], acc[mf][nf], 0, 0, 0);
    __syncthreads();
  }

  int chunk = blockIdx.x * 4 + wave;
  #pragma unroll
  for (int mf = 0; mf < 5; mf++)
    #pragma unroll
    for (int r = 0; r < 4; r++) {
      float mx = fmaxf(fmaxf(acc[mf][0][r], acc[mf][1][r]),
                       fmaxf(acc[mf][2][r], acc[mf][3][r]));
      #pragma unroll
      for (int off = 1; off < 16; off <<= 1) mx = fmaxf(mx, __shfl_xor(mx, off));
      float se = expf(acc[mf][0][r] - mx) + expf(acc[mf][1][r] - mx) +
                 expf(acc[mf][2][r] - mx) + expf(acc[mf][3][r] - mx);
      #pragma unroll
      for (int off = 1; off < 16; off <<= 1) se += __shfl_xor(se, off);
      if (l15 == 0) {
        int row = mf * 16 + l16 * 4 + r;
        size_t pi = ((size_t)row * kNChunk + chunk) * 2;
        part[pi] = mx; part[pi + 1] = se;
      }
    }
}

// ---------------- final: label logits + logsumexp combine + output ----------------
__global__ __launch_bounds__(64) void k_final(const float* __restrict__ part,
                                              const u16* __restrict__ hs,
                                              const float* __restrict__ lm,
                                              const int* __restrict__ label_ids,
                                              float* __restrict__ out) {
  int n = blockIdx.x;
  int lab = n / kB, b = n - lab * kB;
  int lane = threadIdx.x;
  float res = 0.f;
  for (int li = 0; li < kLBL; li++) {
    int r = n * kLBL + li;
    int tok = label_ids[lab * kLBL + li];
    float dv = 0.f;
    for (int d2 = lane; d2 < kD; d2 += 64)
      dv += bf2f(hs[(size_t)r * kD + d2]) * lm[(size_t)d2 * kV + tok];
    #pragma unroll
    for (int o2 = 1; o2 < 64; o2 <<= 1) dv += __shfl_xor(dv, o2);
    const float* pr = part + (size_t)r * kNChunk * 2;
    float mx = -1e30f;
    for (int c = lane; c < kNChunk; c += 64) mx = fmaxf(mx, pr[c * 2]);
    #pragma unroll
    for (int o2 = 1; o2 < 64; o2 <<= 1) mx = fmaxf(mx, __shfl_xor(mx, o2));
    float sum = 0.f;
    for (int c = lane; c < kNChunk; c += 64) sum += pr[c * 2 + 1] * expf(pr[c * 2] - mx);
    #pragma unroll
    for (int o2 = 1; o2 < 64; o2 <<= 1) sum += __shfl_xor(sum, o2);
    res += dv - (mx + logf(sum));
  }
  if (lane == 0) out[b * kNLAB + lab] = res;
}

extern "C" void kernel_launch(void* const* d_in, const int* in_sizes, int n_in,
                              void* d_out, int out_size, void* d_ws, size_t ws_size,
                              hipStream_t stream) {
  const int*   input_ids    = (const int*)d_in[0];
  const int*   label_ids    = (const int*)d_in[1];
  const float* emb          = (const float*)d_in[2];
  const float* wq           = (const float*)d_in[3];
  const float* wk           = (const float*)d_in[4];
  const float* wv           = (const float*)d_in[5];
  const float* wo           = (const float*)d_in[6];
  const float* w1           = (const float*)d_in[7];
  const float* w2           = (const float*)d_in[8];
  const float* w3           = (const float*)d_in[9];
  const float* attn_norm_w  = (const float*)d_in[10];
  const float* ffn_norm_w   = (const float*)d_in[11];
  const float* final_norm_w = (const float*)d_in[12];
  const float* lm_head      = (const float*)d_in[13];
  float* out = (float*)d_out;

  char* ws = (char*)d_ws;
  float* h    = (float*)(ws);                  // 20,971,520 B fp32
  u16*   xn   = (u16*)(ws + 20971520);         // 10,485,760 bf16 (tiled Kt=8)
  u16*   qkv  = (u16*)(ws + 31457280);         // 31,457,280 bf16 [kNS][1536] plain
  u16*   big  = (u16*)(ws + 62914560);         // 28,835,840 (attn-out tiled Kt=8 / ffn act tiled Kt=22)
  u16*   hsb  = (u16*)(ws + 91750400);         // 81,920 plain [80][512]
  float* part = (float*)(ws + 91832320);       // 1,280,000
  u16*   wT   = (u16*)(ws + 93112640);         // 12,845,056 (tiled)

  k_wtrans_all<<<2 * 3136, 256, 0, stream>>>(wq, wk, wv, wo, w1, w3, w2, wT);
  k_embed<<<kNS, 128, 0, stream>>>(input_ids, label_ids, emb, h);

  for (int l = 0; l < kNL; l++) {
    u16* base = wT + (size_t)l * kPL;
    k_rmsnorm<<<kNS, 256, 0, stream>>>(h, attn_norm_w + (size_t)l * kD, xn);
    k_gemm_qkv<<<960, 256, 0, stream>>>(xn, base + oWQ, qkv);
    dim3 gattn(kS / 64, kNSeq * kNH);
    k_attn_mfma<<<gattn, 256, 0, stream>>>(qkv, big);
    k_gemm_n64<<<640, 256, 0, stream>>>(big, base + oWO, h, 8, kD);
    k_rmsnorm<<<kNS, 256, 0, stream>>>(h, ffn_norm_w + (size_t)l * kD, xn);
    k_ffn13_bf16<<<880, 256, 0, stream>>>(xn, base + oW1, base + oW3, big);
    k_gemm_n64<<<640, 256, 0, stream>>>(big, base + oW2, h, 22, kD);
  }

  k_rms_gather<<<kNSeq * kLBL, 256, 0, stream>>>(h, final_norm_w, hsb);
  k_logits_mfma<<<kV / 256, 256, 0, stream>>>(hsb, lm_head, part);
  k_final<<<kNSeq, 64, 0, stream>>>(part, hsb, lm_head, label_ids, out);
}